// Round 6
// baseline (348.027 us; speedup 1.0000x reference)
//
#include <hip/hip_runtime.h>
#include <hip/hip_bf16.h>

#define BB 8
#define CC 512
#define SS 64
#define TT 128
#define DD 256
#define PP 8
#define BS (BB*SS)            // 512
#define NSTAT (BB*CC*SS)      // 262144
#define EPSV 1e-5f

typedef float f32x4 __attribute__((ext_vector_type(4)));
typedef __bf16 bf16x8 __attribute__((ext_vector_type(8)));

__device__ __forceinline__ unsigned short f2bf(float f) {
  unsigned u = __float_as_uint(f);
  u += 0x7FFFu + ((u >> 16) & 1u);
  return (unsigned short)(u >> 16);
}
__device__ __forceinline__ float bf2f(unsigned short h) {
  return __uint_as_float(((unsigned)h) << 16);
}

// ---- K1: per-block BN partials (coalesced [bid][128]) + bf16 stash of x. grid 2048 ----
__global__ __launch_bounds__(256) void k1_stats(const float* __restrict__ x,
    float* __restrict__ csum_part, float* __restrict__ ssq_part,
    unsigned short* __restrict__ xbf) {
  int bid = blockIdx.x;
  int bs = bid >> 2, cq = bid & 3;
  int b = bs >> 6, s = bs & 63;
  const float* xb = x + ((size_t)b * CC * SS + s) * TT;
  unsigned short* xo = xbf + ((size_t)b * CC * SS + s) * TT;
  int tid = threadIdx.x;
  int t4 = tid & 31, coff = tid >> 5;
  float cs0=0,cs1=0,cs2=0,cs3=0, ss0=0,ss1=0,ss2=0,ss3=0;
  #pragma unroll 8
  for (int k = 0; k < 16; k++) {
    int c = cq*128 + coff + k*8;
    float4 v = *reinterpret_cast<const float4*>(xb + (size_t)c*(SS*TT) + t4*4);
    ushort4 o; o.x=f2bf(v.x); o.y=f2bf(v.y); o.z=f2bf(v.z); o.w=f2bf(v.w);
    *reinterpret_cast<ushort4*>(xo + (size_t)c*(SS*TT) + t4*4) = o;
    cs0 += v.x; cs1 += v.y; cs2 += v.z; cs3 += v.w;
    ss0 += v.x*v.x; ss1 += v.y*v.y; ss2 += v.z*v.z; ss3 += v.w*v.w;
  }
  __shared__ float4 redC[256];
  __shared__ float4 redS[256];
  redC[tid] = make_float4(cs0,cs1,cs2,cs3);
  redS[tid] = make_float4(ss0,ss1,ss2,ss3);
  __syncthreads();
  if (tid < 32) {
    #pragma unroll
    for (int j = 1; j < 8; j++) {
      float4 a = redC[tid + j*32], bq = redS[tid + j*32];
      cs0+=a.x; cs1+=a.y; cs2+=a.z; cs3+=a.w;
      ss0+=bq.x; ss1+=bq.y; ss2+=bq.z; ss3+=bq.w;
    }
    *reinterpret_cast<float4*>(csum_part + (size_t)bid*TT + tid*4) = make_float4(cs0,cs1,cs2,cs3);
    *reinterpret_cast<float4*>(ssq_part  + (size_t)bid*TT + tid*4) = make_float4(ss0,ss1,ss2,ss3);
  }
}

// ---- K1b: reduce partials -> sumt/sumsq. grid 128 ----
__global__ __launch_bounds__(256) void k1b_reduce(
    const float* __restrict__ csum_part, const float* __restrict__ ssq_part,
    float* __restrict__ sumt, float* __restrict__ sumsq) {
  int t = blockIdx.x, tid = threadIdx.x;
  float cs = 0.f, ss = 0.f;
  #pragma unroll
  for (int k=0;k<8;k++) {
    int bidk = tid + k*256;
    cs += csum_part[(size_t)bidk*TT + t];
    ss += ssq_part[(size_t)bidk*TT + t];
  }
  #pragma unroll
  for (int off=32; off; off>>=1) { cs += __shfl_xor(cs,off); ss += __shfl_xor(ss,off); }
  __shared__ float redc[4], reds[4];
  int wave = tid >> 6, lane = tid & 63;
  if (lane == 0) { redc[wave] = cs; reds[wave] = ss; }
  __syncthreads();
  if (tid == 0) {
    sumt[t]  = redc[0]+redc[1]+redc[2]+redc[3];
    sumsq[t] = reds[0]+reds[1]+reds[2]+reds[3];
  }
}

// ---- K2a: route1 -> a1 (global) + b1. grid 512 ----
__global__ __launch_bounds__(256) void k2a_route1(
    const float* __restrict__ sumt, const float* __restrict__ sumsq,
    const float* __restrict__ csum_part, const float* __restrict__ gamma,
    const float* __restrict__ beta, const float* __restrict__ keys1,
    const float* __restrict__ bp1, float* __restrict__ a1g,
    float* __restrict__ b1) {
  int bs = blockIdx.x, tid = threadIdx.x;
  __shared__ float a1s[PP];
  if (tid < 64) {
    float pv0, pv1;
    {
      int t = tid;
      float cs = csum_part[(size_t)(bs*4+0)*TT+t] + csum_part[(size_t)(bs*4+1)*TT+t]
               + csum_part[(size_t)(bs*4+2)*TT+t] + csum_part[(size_t)(bs*4+3)*TT+t];
      float m = sumt[t] * (1.f/NSTAT);
      float var = sumsq[t]*(1.f/NSTAT) - m*m;
      float g = gamma[t] * rsqrtf(var + EPSV);
      pv0 = (cs*(1.f/CC) - m)*g + beta[t];
    }
    {
      int t = tid + 64;
      float cs = csum_part[(size_t)(bs*4+0)*TT+t] + csum_part[(size_t)(bs*4+1)*TT+t]
               + csum_part[(size_t)(bs*4+2)*TT+t] + csum_part[(size_t)(bs*4+3)*TT+t];
      float m = sumt[t] * (1.f/NSTAT);
      float var = sumsq[t]*(1.f/NSTAT) - m*m;
      float g = gamma[t] * rsqrtf(var + EPSV);
      pv1 = (cs*(1.f/CC) - m)*g + beta[t];
    }
    float ssq = pv0*pv0 + pv1*pv1;
    #pragma unroll
    for (int off=32; off; off>>=1) ssq += __shfl_xor(ssq, off);
    float pn = sqrtf(ssq) + 1e-8f;
    float lg[PP];
    #pragma unroll
    for (int p=0;p<PP;p++) {
      float k0 = keys1[p*TT + tid], k1 = keys1[p*TT + tid + 64];
      float dot = pv0*k0 + pv1*k1;
      float kn = k0*k0 + k1*k1;
      #pragma unroll
      for (int off=32; off; off>>=1) { dot += __shfl_xor(dot,off); kn += __shfl_xor(kn,off); }
      lg[p] = dot / (pn * (sqrtf(kn) + 1e-8f));
    }
    if (tid == 0) {
      float mx = lg[0];
      #pragma unroll
      for (int p=1;p<PP;p++) mx = fmaxf(mx, lg[p]);
      float se = 0.f, e[PP];
      #pragma unroll
      for (int p=0;p<PP;p++){ e[p] = __expf(lg[p]-mx); se += e[p]; }
      float inv = 1.f/se;
      #pragma unroll
      for (int p=0;p<PP;p++) a1s[p] = e[p]*inv;
    }
  }
  __syncthreads();
  if (tid < PP) a1g[bs*PP + tid] = a1s[tid];
  float bacc = 0.f;
  #pragma unroll
  for (int p=0;p<PP;p++) bacc += a1s[p]*bp1[p*DD + tid];
  b1[(size_t)bs*DD + tid] = bacc;
}

// ---- Kmix: w[bs] = sum_p a[bs][p] * Wp[p] (32768 elems). grid 512 (32 chunks x 16 bs-groups) ----
__global__ __launch_bounds__(256) void kmix(
    const float* __restrict__ Wp, const float* __restrict__ ag,
    float* __restrict__ wout, unsigned short* __restrict__ wbf) {
  int bid = blockIdx.x;
  int chunk = bid & 31;      // 32 chunks x 1024 elems
  int bsg = bid >> 5;        // 16 groups x 32 bs
  int tid = threadIdx.x;
  int e = chunk*1024 + tid*4;
  float4 w[PP];
  #pragma unroll
  for (int p=0;p<PP;p++) w[p] = *reinterpret_cast<const float4*>(Wp + (size_t)p*32768 + e);
  __shared__ float as[256];
  as[tid] = ag[bsg*256 + tid];   // 32 bs x 8 a-values
  __syncthreads();
  #pragma unroll 4
  for (int i=0;i<32;i++) {
    int bs = bsg*32 + i;
    float4 acc = make_float4(0.f,0.f,0.f,0.f);
    #pragma unroll
    for (int p=0;p<PP;p++) {
      float a = as[i*8+p];
      acc.x += a*w[p].x; acc.y += a*w[p].y; acc.z += a*w[p].z; acc.w += a*w[p].w;
    }
    size_t off = (size_t)bs*32768 + e;
    *reinterpret_cast<float4*>(wout + off) = acc;
    ushort4 o; o.x=f2bf(acc.x); o.y=f2bf(acc.y); o.z=f2bf(acc.z); o.w=f2bf(acc.w);
    *reinterpret_cast<ushort4*>(wbf + off) = o;
  }
}

// ---- K3: GEMM1 Z = relu(BN(x) @ W1^T + b1) + pooled2 partials. grid 2048, 1024 thr ----
__global__ __launch_bounds__(1024) void k3_gemm1(
    const unsigned short* __restrict__ xbf, const float* __restrict__ sumt,
    const float* __restrict__ sumsq, const float* __restrict__ gamma,
    const float* __restrict__ beta, const unsigned short* __restrict__ w1bf,
    const float* __restrict__ b1, unsigned short* __restrict__ zbf,
    float* __restrict__ p2part) {
  int bid = blockIdx.x;
  int bs = bid >> 2, mt = bid & 3;
  int b = bs >> 6, s = bs & 63;
  __shared__ unsigned short lA[128*128];   // 32 KB, row 256 B, swizzled
  __shared__ unsigned short lB[256*128];   // 64 KB, row 256 B, swizzled; reused for z-tile
  __shared__ float mean_s[TT], g_s[TT], beta_s[TT];
  int tid = threadIdx.x;
  char* lAc = reinterpret_cast<char*>(lA);
  char* lBc = reinterpret_cast<char*>(lB);
  // issue all staging loads first (two-phase: max outstanding)
  const unsigned short* xb = xbf + (((size_t)b*CC + mt*128)*SS + s)*TT;
  const unsigned short* wsrc = w1bf + (size_t)bs*(DD*TT);
  uint4 ta[2], tb[4];
  #pragma unroll
  for (int i=0;i<2;i++) {
    int flat = tid + i*1024;
    int r = flat >> 4, c8 = flat & 15;
    ta[i] = *reinterpret_cast<const uint4*>(xb + (size_t)r*(SS*TT) + c8*8);
  }
  #pragma unroll
  for (int i=0;i<4;i++) {
    int flat = tid + i*1024;
    tb[i] = *reinterpret_cast<const uint4*>(wsrc + (size_t)flat*8);
  }
  if (tid < TT) {
    float m = sumt[tid]*(1.f/NSTAT);
    float var = sumsq[tid]*(1.f/NSTAT) - m*m;
    mean_s[tid] = m;
    g_s[tid] = gamma[tid]*rsqrtf(var+EPSV);
    beta_s[tid] = beta[tid];
  }
  __syncthreads();
  // write B
  #pragma unroll
  for (int i=0;i<4;i++) {
    int flat = tid + i*1024;
    int n = flat >> 4, ch = flat & 15;
    unsigned addr = (unsigned)(n*256) + (((unsigned)(ch*16)) ^ (((unsigned)(n&7))<<4));
    *reinterpret_cast<uint4*>(lBc + addr) = tb[i];
  }
  // convert + write A
  auto bn2 = [&](unsigned pair, int t0) -> unsigned {
    float lo = bf2f((unsigned short)(pair & 0xFFFFu));
    float hi = bf2f((unsigned short)(pair >> 16));
    lo = (lo - mean_s[t0])*g_s[t0] + beta_s[t0];
    hi = (hi - mean_s[t0+1])*g_s[t0+1] + beta_s[t0+1];
    return ((unsigned)f2bf(hi) << 16) | (unsigned)f2bf(lo);
  };
  #pragma unroll
  for (int i=0;i<2;i++) {
    int flat = tid + i*1024;
    int r = flat >> 4, c8 = flat & 15;
    int t0 = c8*8;
    uint4 o;
    o.x = bn2(ta[i].x, t0); o.y = bn2(ta[i].y, t0+2);
    o.z = bn2(ta[i].z, t0+4); o.w = bn2(ta[i].w, t0+6);
    unsigned addr = (unsigned)(r*256) + (((unsigned)(c8*16)) ^ (((unsigned)(r&7))<<4));
    *reinterpret_cast<uint4*>(lAc + addr) = o;
  }
  __syncthreads();
  int wave = tid >> 6, lane = tid & 63;
  int wm = wave >> 3, wn = wave & 7;     // 2 x 8 waves, per-wave tile 64 x 32
  int lr = lane & 15, kg = lane >> 4;
  f32x4 zero = {0.f,0.f,0.f,0.f};
  f32x4 acc[4][2];
  #pragma unroll
  for (int m=0;m<4;m++)
    #pragma unroll
    for (int n=0;n<2;n++) acc[m][n] = zero;
  #pragma unroll
  for (int k0=0;k0<128;k0+=32) {
    bf16x8 af[4], bfr[2];
    #pragma unroll
    for (int m=0;m<4;m++) {
      int row = wm*64 + m*16 + lr;
      unsigned addr = (unsigned)(row*256) + (((unsigned)(k0*2 + kg*16)) ^ (((unsigned)(row&7))<<4));
      af[m] = *reinterpret_cast<const bf16x8*>(lAc + addr);
    }
    #pragma unroll
    for (int n=0;n<2;n++) {
      int row = wn*32 + n*16 + lr;
      unsigned addr = (unsigned)(row*256) + (((unsigned)(k0*2 + kg*16)) ^ (((unsigned)(row&7))<<4));
      bfr[n] = *reinterpret_cast<const bf16x8*>(lBc + addr);
    }
    #pragma unroll
    for (int m=0;m<4;m++)
      #pragma unroll
      for (int n=0;n<2;n++)
        acc[m][n] = __builtin_amdgcn_mfma_f32_16x16x32_bf16(af[m], bfr[n], acc[m][n], 0, 0, 0);
  }
  // epilogue: +b1, relu, pooled2 partials; z-tile -> LDS (swizzled, reuse lB) -> coalesced stores
  const float* b1p = b1 + (size_t)bs*DD;
  float* p2p = p2part + (((size_t)bid*2) + wm)*DD;
  __syncthreads();   // everyone done reading lB
  #pragma unroll
  for (int n=0;n<2;n++) {
    int d = wn*32 + n*16 + lr;
    float bv = b1p[d];
    float csum = 0.f;
    #pragma unroll
    for (int m=0;m<4;m++) {
      int rbase = wm*64 + m*16 + kg*4;
      #pragma unroll
      for (int j=0;j<4;j++) {
        float v = fmaxf(acc[m][n][j] + bv, 0.f);
        int row = rbase + j;
        unsigned addr = (unsigned)(row*512) + (((unsigned)(d*2)) ^ (((unsigned)(row&7))<<4));
        *reinterpret_cast<unsigned short*>(lBc + addr) = f2bf(v);
        csum += v;
      }
    }
    csum += __shfl_xor(csum, 16);
    csum += __shfl_xor(csum, 32);
    if (kg == 0) p2p[d] = csum;
  }
  __syncthreads();
  unsigned short* zb = zbf + (((size_t)b*CC + mt*128)*SS + s)*DD;
  #pragma unroll
  for (int i=0;i<4;i++) {
    int flat = tid + i*1024;
    int r = flat >> 5, ch = flat & 31;
    unsigned addr = (unsigned)(r*512) + (((unsigned)(ch*16)) ^ (((unsigned)(r&7))<<4));
    uint4 v = *reinterpret_cast<const uint4*>(lBc + addr);
    *reinterpret_cast<uint4*>(zb + (size_t)r*(SS*DD) + ch*8) = v;
  }
}

// ---- K4a: route2 -> a2 (global) + b2. grid 512 ----
__global__ __launch_bounds__(256) void k4a_route2(
    const float* __restrict__ p2part, const float* __restrict__ keys2,
    const float* __restrict__ bp2, float* __restrict__ a2g,
    float* __restrict__ b2) {
  int bs = blockIdx.x, tid = threadIdx.x;
  __shared__ float pvs[DD];
  __shared__ float a2s[PP];
  {
    float s8 = 0.f;
    #pragma unroll
    for (int r=0;r<8;r++) s8 += p2part[((size_t)bs*8 + r)*DD + tid];
    pvs[tid] = s8 * (1.f/CC);
  }
  __syncthreads();
  if (tid < 64) {
    float pv[4]; float ssq = 0.f;
    #pragma unroll
    for (int j=0;j<4;j++) { pv[j] = pvs[tid + 64*j]; ssq += pv[j]*pv[j]; }
    #pragma unroll
    for (int off=32; off; off>>=1) ssq += __shfl_xor(ssq, off);
    float pn = sqrtf(ssq) + 1e-8f;
    float lg[PP];
    #pragma unroll
    for (int p=0;p<PP;p++) {
      float dot = 0.f, kn = 0.f;
      #pragma unroll
      for (int j=0;j<4;j++) {
        float kv = keys2[p*DD + tid + 64*j];
        dot += pv[j]*kv; kn += kv*kv;
      }
      #pragma unroll
      for (int off=32; off; off>>=1) { dot += __shfl_xor(dot,off); kn += __shfl_xor(kn,off); }
      lg[p] = dot / (pn * (sqrtf(kn)+1e-8f));
    }
    if (tid == 0) {
      float mx = lg[0];
      #pragma unroll
      for (int p=1;p<PP;p++) mx = fmaxf(mx,lg[p]);
      float se=0.f, e[PP];
      #pragma unroll
      for (int p=0;p<PP;p++){ e[p]=__expf(lg[p]-mx); se+=e[p]; }
      float inv = 1.f/se;
      #pragma unroll
      for (int p=0;p<PP;p++) a2s[p]=e[p]*inv;
    }
  }
  __syncthreads();
  if (tid < PP) a2g[bs*PP + tid] = a2s[tid];
  if (tid < TT) {
    float bacc = 0.f;
    #pragma unroll
    for (int p=0;p<PP;p++) bacc += a2s[p]*bp2[p*TT + tid];
    b2[(size_t)bs*TT + tid] = bacc;
  }
}

// ---- K5: GEMM2 out = x + Z @ W2^T + b2. grid 2048, 1024 thr ----
__global__ __launch_bounds__(1024) void k5_gemm2(
    const unsigned short* __restrict__ zbf, const unsigned short* __restrict__ w2bf,
    const float* __restrict__ b2, const unsigned short* __restrict__ xbf,
    float* __restrict__ out) {
  int bid = blockIdx.x;
  int bs = bid >> 2, mt = bid & 3;
  int b = bs >> 6, s = bs & 63;
  __shared__ unsigned short lA[128*256];   // 64 KB, row 512 B, swizzled; reused for fp32 out-tile
  __shared__ unsigned short lB[128*256];   // 64 KB, row 512 B, swizzled
  int tid = threadIdx.x;
  char* lAc = reinterpret_cast<char*>(lA);
  char* lBc = reinterpret_cast<char*>(lB);
  const unsigned short* za = zbf + (((size_t)b*CC + mt*128)*SS + s)*DD;
  const unsigned short* wsrc = w2bf + (size_t)bs*(TT*DD);
  uint4 ta[4], tb[4];
  #pragma unroll
  for (int i=0;i<4;i++) {
    int flat = tid + i*1024;
    int r = flat >> 5, ch = flat & 31;
    ta[i] = *reinterpret_cast<const uint4*>(za + (size_t)r*(SS*DD) + ch*8);
  }
  #pragma unroll
  for (int i=0;i<4;i++) {
    int flat = tid + i*1024;
    tb[i] = *reinterpret_cast<const uint4*>(wsrc + (size_t)flat*8);
  }
  #pragma unroll
  for (int i=0;i<4;i++) {
    int flat = tid + i*1024;
    int r = flat >> 5, ch = flat & 31;
    unsigned addr = (unsigned)(r*512) + (((unsigned)(ch*16)) ^ (((unsigned)(r&7))<<4));
    *reinterpret_cast<uint4*>(lAc + addr) = ta[i];
  }
  #pragma unroll
  for (int i=0;i<4;i++) {
    int flat = tid + i*1024;
    int r = flat >> 5, ch = flat & 31;
    unsigned addr = (unsigned)(r*512) + (((unsigned)(ch*16)) ^ (((unsigned)(r&7))<<4));
    *reinterpret_cast<uint4*>(lBc + addr) = tb[i];
  }
  __syncthreads();
  int wave = tid >> 6, lane = tid & 63;
  int wm = wave >> 2, wn = wave & 3;     // 4 x 4 waves, per-wave tile 32 x 32
  int lr = lane & 15, kg = lane >> 4;
  f32x4 zero = {0.f,0.f,0.f,0.f};
  f32x4 acc[2][2];
  #pragma unroll
  for (int m=0;m<2;m++)
    #pragma unroll
    for (int n=0;n<2;n++) acc[m][n] = zero;
  #pragma unroll
  for (int k0=0;k0<256;k0+=32) {
    bf16x8 af[2], bfr[2];
    #pragma unroll
    for (int m=0;m<2;m++) {
      int row = wm*32 + m*16 + lr;
      unsigned addr = (unsigned)(row*512) + (((unsigned)(k0*2 + kg*16)) ^ (((unsigned)(row&7))<<4));
      af[m] = *reinterpret_cast<const bf16x8*>(lAc + addr);
    }
    #pragma unroll
    for (int n=0;n<2;n++) {
      int row = wn*32 + n*16 + lr;
      unsigned addr = (unsigned)(row*512) + (((unsigned)(k0*2 + kg*16)) ^ (((unsigned)(row&7))<<4));
      bfr[n] = *reinterpret_cast<const bf16x8*>(lBc + addr);
    }
    #pragma unroll
    for (int m=0;m<2;m++)
      #pragma unroll
      for (int n=0;n<2;n++)
        acc[m][n] = __builtin_amdgcn_mfma_f32_16x16x32_bf16(af[m], bfr[n], acc[m][n], 0, 0, 0);
  }
  // epilogue: +b2 -> fp32 out-tile in LDS (swizzled, reuse lA) -> residual + coalesced float4 stores
  const float* b2p = b2 + (size_t)bs*TT;
  __syncthreads();   // done reading lA
  #pragma unroll
  for (int n=0;n<2;n++) {
    int t = wn*32 + n*16 + lr;
    float bv = b2p[t];
    #pragma unroll
    for (int m=0;m<2;m++) {
      int rbase = wm*32 + m*16 + kg*4;
      #pragma unroll
      for (int j=0;j<4;j++) {
        int row = rbase + j;
        unsigned addr = (unsigned)(row*512) + (((unsigned)(t*4)) ^ (((unsigned)(row&7))<<4));
        *reinterpret_cast<float*>(lAc + addr) = acc[m][n][j] + bv;
      }
    }
  }
  __syncthreads();
  const unsigned short* xb = xbf + (((size_t)b*CC + mt*128)*SS + s)*TT;
  float* ob = out + (((size_t)b*CC + mt*128)*SS + s)*TT;
  #pragma unroll
  for (int i=0;i<4;i++) {
    int flat = tid + i*1024;
    int r = flat >> 5, c4 = flat & 31;
    unsigned addr = (unsigned)(r*512) + (((unsigned)(c4*16)) ^ (((unsigned)(r&7))<<4));
    float4 v = *reinterpret_cast<const float4*>(lAc + addr);
    ushort4 xv = *reinterpret_cast<const ushort4*>(xb + (size_t)r*(SS*TT) + c4*4);
    v.x += bf2f(xv.x); v.y += bf2f(xv.y); v.z += bf2f(xv.z); v.w += bf2f(xv.w);
    *reinterpret_cast<float4*>(ob + (size_t)r*(SS*TT) + c4*4) = v;
  }
}

extern "C" void kernel_launch(void* const* d_in, const int* in_sizes, int n_in,
                              void* d_out, int out_size, void* d_ws, size_t ws_size,
                              hipStream_t stream) {
  (void)in_sizes; (void)n_in; (void)out_size; (void)ws_size;
  const float* x     = (const float*)d_in[0];
  const float* gamma = (const float*)d_in[1];
  const float* beta  = (const float*)d_in[2];
  const float* keys1 = (const float*)d_in[3];
  const float* Wp1   = (const float*)d_in[4];
  const float* bp1   = (const float*)d_in[5];
  const float* keys2 = (const float*)d_in[6];
  const float* Wp2   = (const float*)d_in[7];
  const float* bp2   = (const float*)d_in[8];
  float* out = (float*)d_out;
  char* ws = (char*)d_ws;

  // ws layout (bytes):
  float* sumt        = (float*)(ws + 0);              // 512 B
  float* sumsq       = (float*)(ws + 512);            // 512 B
  float* csum_part   = (float*)(ws + 1024);           // 1 MB (2048 x 128, coalesced)
  float* ssq_part    = (float*)(ws + 1049600);        // 1 MB
  float* p2part      = (float*)(ws + 2098176);        // 4 MB (512 x 8 x 256)
  float* a1g         = (float*)(ws + 6292480);        // 16 KB
  float* a2g         = (float*)(ws + 6308864);        // 16 KB
  float* b1          = (float*)(ws + 6325248);        // 512 KB
  float* b2          = (float*)(ws + 6849536);        // 256 KB
  unsigned short* w1bf = (unsigned short*)(ws + 7111680);   // 33.5 MB
  unsigned short* w2bf = (unsigned short*)(ws + 40666112);  // 33.5 MB
  unsigned short* xbf  = (unsigned short*)(ws + 74220544);  // 67 MB
  unsigned short* zbf  = (unsigned short*)(ws + 141329408); // 134 MB -> end ~275 MB

  float* w1out = out + 33554432;
  float* w2out = out + 50331648;

  k1_stats  <<<BS*4, 256,  0, stream>>>(x, csum_part, ssq_part, xbf);
  k1b_reduce<<<TT,   256,  0, stream>>>(csum_part, ssq_part, sumt, sumsq);
  k2a_route1<<<BS,   256,  0, stream>>>(sumt, sumsq, csum_part, gamma, beta, keys1, bp1,
                                        a1g, b1);
  kmix      <<<512,  256,  0, stream>>>(Wp1, a1g, w1out, w1bf);
  k3_gemm1  <<<BS*4, 1024, 0, stream>>>(xbf, sumt, sumsq, gamma, beta, w1bf, b1, zbf, p2part);
  k4a_route2<<<BS,   256,  0, stream>>>(p2part, keys2, bp2, a2g, b2);
  kmix      <<<512,  256,  0, stream>>>(Wp2, a2g, w2out, w2bf);
  k5_gemm2  <<<BS*4, 1024, 0, stream>>>(zbf, w2bf, b2, xbf, out);
}

// Round 7
// 340.639 us; speedup vs baseline: 1.0217x; 1.0217x over previous
//
#include <hip/hip_runtime.h>
#include <hip/hip_bf16.h>

#define BB 8
#define CC 512
#define SS 64
#define TT 128
#define DD 256
#define PP 8
#define BS (BB*SS)            // 512
#define NSTAT (BB*CC*SS)      // 262144
#define EPSV 1e-5f

typedef float f32x4 __attribute__((ext_vector_type(4)));
typedef __bf16 bf16x8 __attribute__((ext_vector_type(8)));

__device__ __forceinline__ unsigned short f2bf(float f) {
  unsigned u = __float_as_uint(f);
  u += 0x7FFFu + ((u >> 16) & 1u);
  return (unsigned short)(u >> 16);
}
__device__ __forceinline__ float bf2f(unsigned short h) {
  return __uint_as_float(((unsigned)h) << 16);
}

// ---- K1: per-block BN partials (transposed, no atomics) + bf16 stash of x. grid 2048 ----
__global__ __launch_bounds__(256) void k1_stats(const float* __restrict__ x,
    float* __restrict__ csum_part, float* __restrict__ ssq_part,
    unsigned short* __restrict__ xbf) {
  int bid = blockIdx.x;
  int bs = bid >> 2, cq = bid & 3;
  int b = bs >> 6, s = bs & 63;
  const float* xb = x + ((size_t)b * CC * SS + s) * TT;
  unsigned short* xo = xbf + ((size_t)b * CC * SS + s) * TT;
  int tid = threadIdx.x;
  int t4 = tid & 31, coff = tid >> 5;
  float cs0=0,cs1=0,cs2=0,cs3=0, ss0=0,ss1=0,ss2=0,ss3=0;
  #pragma unroll 8
  for (int k = 0; k < 16; k++) {
    int c = cq*128 + coff + k*8;
    float4 v = *reinterpret_cast<const float4*>(xb + (size_t)c*(SS*TT) + t4*4);
    ushort4 o; o.x=f2bf(v.x); o.y=f2bf(v.y); o.z=f2bf(v.z); o.w=f2bf(v.w);
    *reinterpret_cast<ushort4*>(xo + (size_t)c*(SS*TT) + t4*4) = o;
    cs0 += v.x; cs1 += v.y; cs2 += v.z; cs3 += v.w;
    ss0 += v.x*v.x; ss1 += v.y*v.y; ss2 += v.z*v.z; ss3 += v.w*v.w;
  }
  __shared__ float4 redC[256];
  __shared__ float4 redS[256];
  redC[tid] = make_float4(cs0,cs1,cs2,cs3);
  redS[tid] = make_float4(ss0,ss1,ss2,ss3);
  __syncthreads();
  if (tid < 32) {
    #pragma unroll
    for (int j = 1; j < 8; j++) {
      float4 a = redC[tid + j*32], bq = redS[tid + j*32];
      cs0+=a.x; cs1+=a.y; cs2+=a.z; cs3+=a.w;
      ss0+=bq.x; ss1+=bq.y; ss2+=bq.z; ss3+=bq.w;
    }
    int t0 = tid*4;
    csum_part[(size_t)(t0+0)*2048 + bid] = cs0;
    csum_part[(size_t)(t0+1)*2048 + bid] = cs1;
    csum_part[(size_t)(t0+2)*2048 + bid] = cs2;
    csum_part[(size_t)(t0+3)*2048 + bid] = cs3;
    ssq_part[(size_t)(t0+0)*2048 + bid] = ss0;
    ssq_part[(size_t)(t0+1)*2048 + bid] = ss1;
    ssq_part[(size_t)(t0+2)*2048 + bid] = ss2;
    ssq_part[(size_t)(t0+3)*2048 + bid] = ss3;
  }
}

// ---- K1b: reduce partials -> sumt/sumsq. grid 128 ----
__global__ __launch_bounds__(256) void k1b_reduce(
    const float* __restrict__ csum_part, const float* __restrict__ ssq_part,
    float* __restrict__ sumt, float* __restrict__ sumsq) {
  int t = blockIdx.x, tid = threadIdx.x;
  const float* cp = csum_part + (size_t)t*2048;
  const float* sp = ssq_part + (size_t)t*2048;
  float cs = 0.f, ss = 0.f;
  #pragma unroll
  for (int k=0;k<8;k++) { cs += cp[tid + k*256]; ss += sp[tid + k*256]; }
  #pragma unroll
  for (int off=32; off; off>>=1) { cs += __shfl_xor(cs,off); ss += __shfl_xor(ss,off); }
  __shared__ float redc[4], reds[4];
  int wave = tid >> 6, lane = tid & 63;
  if (lane == 0) { redc[wave] = cs; reds[wave] = ss; }
  __syncthreads();
  if (tid == 0) {
    sumt[t]  = redc[0]+redc[1]+redc[2]+redc[3];
    sumsq[t] = reds[0]+reds[1]+reds[2]+reds[3];
  }
}

// ---- K2: route1 -> a1 (redundant per q), write w1out fp32 + w1bf + b1 quarter. grid 2048 ----
__global__ __launch_bounds__(256) void k2_route1(
    const float* __restrict__ sumt, const float* __restrict__ sumsq,
    const float* __restrict__ csum_part, const float* __restrict__ gamma,
    const float* __restrict__ beta, const float* __restrict__ keys1,
    const float* __restrict__ Wp1, const float* __restrict__ bp1,
    float* __restrict__ w1out, unsigned short* __restrict__ w1bf,
    float* __restrict__ b1) {
  int bid = blockIdx.x;
  int bs = bid >> 2, q = bid & 3;
  int tid = threadIdx.x;
  __shared__ float a1s[PP];
  if (tid < 64) {
    float pv0, pv1;
    {
      int t = tid;
      float4 c4v = *reinterpret_cast<const float4*>(csum_part + (size_t)t*2048 + bs*4);
      float cs = c4v.x + c4v.y + c4v.z + c4v.w;
      float m = sumt[t] * (1.f/NSTAT);
      float var = sumsq[t]*(1.f/NSTAT) - m*m;
      float g = gamma[t] * rsqrtf(var + EPSV);
      pv0 = (cs*(1.f/CC) - m)*g + beta[t];
    }
    {
      int t = tid + 64;
      float4 c4v = *reinterpret_cast<const float4*>(csum_part + (size_t)t*2048 + bs*4);
      float cs = c4v.x + c4v.y + c4v.z + c4v.w;
      float m = sumt[t] * (1.f/NSTAT);
      float var = sumsq[t]*(1.f/NSTAT) - m*m;
      float g = gamma[t] * rsqrtf(var + EPSV);
      pv1 = (cs*(1.f/CC) - m)*g + beta[t];
    }
    float ssq = pv0*pv0 + pv1*pv1;
    #pragma unroll
    for (int off=32; off; off>>=1) ssq += __shfl_xor(ssq, off);
    float pn = sqrtf(ssq) + 1e-8f;
    float lg[PP];
    #pragma unroll
    for (int p=0;p<PP;p++) {
      float k0 = keys1[p*TT + tid], k1 = keys1[p*TT + tid + 64];
      float dot = pv0*k0 + pv1*k1;
      float kn = k0*k0 + k1*k1;
      #pragma unroll
      for (int off=32; off; off>>=1) { dot += __shfl_xor(dot,off); kn += __shfl_xor(kn,off); }
      lg[p] = dot / (pn * (sqrtf(kn) + 1e-8f));
    }
    if (tid == 0) {
      float mx = lg[0];
      #pragma unroll
      for (int p=1;p<PP;p++) mx = fmaxf(mx, lg[p]);
      float se = 0.f, e[PP];
      #pragma unroll
      for (int p=0;p<PP;p++){ e[p] = __expf(lg[p]-mx); se += e[p]; }
      float inv = 1.f/se;
      #pragma unroll
      for (int p=0;p<PP;p++) a1s[p] = e[p]*inv;
    }
  }
  __syncthreads();
  float a[PP];
  #pragma unroll
  for (int p=0;p<PP;p++) a[p]=a1s[p];
  #pragma unroll
  for (int i=0;i<8;i++) {
    int idx = tid + i*256;
    int dr = idx >> 5, c4 = idx & 31;
    size_t roff = (size_t)(q*64+dr)*TT + c4*4;
    size_t off = (size_t)bs*(DD*TT) + roff;
    float4 accv = make_float4(0.f,0.f,0.f,0.f);
    #pragma unroll
    for (int p=0;p<PP;p++) {
      float4 v = *reinterpret_cast<const float4*>(Wp1 + (size_t)p*(DD*TT) + roff);
      accv.x += a[p]*v.x; accv.y += a[p]*v.y; accv.z += a[p]*v.z; accv.w += a[p]*v.w;
    }
    *reinterpret_cast<float4*>(w1out + off) = accv;
    ushort4 o; o.x=f2bf(accv.x); o.y=f2bf(accv.y); o.z=f2bf(accv.z); o.w=f2bf(accv.w);
    *reinterpret_cast<ushort4*>(w1bf + off) = o;
  }
  if (tid < 64) {
    int d = q*64 + tid;
    float bacc = 0.f;
    #pragma unroll
    for (int p=0;p<PP;p++) bacc += a[p]*bp1[p*DD + d];
    b1[(size_t)bs*DD + d] = bacc;
  }
}

// ---- K3: GEMM1 Z = relu(BN(x) @ W1^T + b1), N-split x2. grid 4096, 512 thr, 64 KB LDS ----
__global__ __launch_bounds__(512, 4) void k3_gemm1(
    const unsigned short* __restrict__ xbf, const float* __restrict__ sumt,
    const float* __restrict__ sumsq, const float* __restrict__ gamma,
    const float* __restrict__ beta, const unsigned short* __restrict__ w1bf,
    const float* __restrict__ b1, unsigned short* __restrict__ zbf,
    float* __restrict__ p2part) {
  int bid = blockIdx.x;
  int bs = bid >> 3, sub = bid & 7;
  int mt = sub >> 1, nh = sub & 1;
  int b = bs >> 6, s = bs & 63;
  __shared__ unsigned short lA[128*128];   // 32 KB, row 256 B, swizzled
  __shared__ unsigned short lB[128*128];   // 32 KB, row 256 B, swizzled; reused for z-half-tile
  __shared__ float mean_s[TT], g_s[TT], beta_s[TT];
  int tid = threadIdx.x;
  if (tid < TT) {
    float m = sumt[tid]*(1.f/NSTAT);
    float var = sumsq[tid]*(1.f/NSTAT) - m*m;
    mean_s[tid] = m;
    g_s[tid] = gamma[tid]*rsqrtf(var+EPSV);
    beta_s[tid] = beta[tid];
  }
  __syncthreads();
  char* lAc = reinterpret_cast<char*>(lA);
  char* lBc = reinterpret_cast<char*>(lB);
  auto bn2 = [&](unsigned pair, int t0) -> unsigned {
    float lo = bf2f((unsigned short)(pair & 0xFFFFu));
    float hi = bf2f((unsigned short)(pair >> 16));
    lo = (lo - mean_s[t0])*g_s[t0] + beta_s[t0];
    hi = (hi - mean_s[t0+1])*g_s[t0+1] + beta_s[t0+1];
    return ((unsigned)f2bf(hi) << 16) | (unsigned)f2bf(lo);
  };
  // stage A (bf16 x -> BN -> bf16): 2048 uint4
  const unsigned short* xb = xbf + (((size_t)b*CC + mt*128)*SS + s)*TT;
  #pragma unroll
  for (int i=0;i<4;i++) {
    int flat = tid + i*512;
    int r = flat >> 4, c8 = flat & 15;
    int t0 = c8*8;
    uint4 v = *reinterpret_cast<const uint4*>(xb + (size_t)r*(SS*TT) + t0);
    uint4 o;
    o.x = bn2(v.x, t0); o.y = bn2(v.y, t0+2); o.z = bn2(v.z, t0+4); o.w = bn2(v.w, t0+6);
    unsigned addr = (unsigned)(r*256) + (((unsigned)(c8*16)) ^ (((unsigned)(r&7))<<4));
    *reinterpret_cast<uint4*>(lAc + addr) = o;
  }
  // stage B: w1bf rows [nh*128, nh*128+128), 2048 uint4
  const unsigned short* wsrc = w1bf + (size_t)bs*(DD*TT);
  #pragma unroll
  for (int i=0;i<4;i++) {
    int flat = tid + i*512;
    int n = flat >> 4, ch = flat & 15;
    uint4 v = *reinterpret_cast<const uint4*>(wsrc + ((size_t)nh*2048 + flat)*8);
    unsigned addr = (unsigned)(n*256) + (((unsigned)(ch*16)) ^ (((unsigned)(n&7))<<4));
    *reinterpret_cast<uint4*>(lBc + addr) = v;
  }
  __syncthreads();
  int wave = tid >> 6, lane = tid & 63;
  int wm = wave >> 2, wn = wave & 3;     // 2 x 4 waves, per-wave tile 64 x 32
  int lr = lane & 15, kg = lane >> 4;
  f32x4 zero = {0.f,0.f,0.f,0.f};
  f32x4 acc[4][2];
  #pragma unroll
  for (int m=0;m<4;m++)
    #pragma unroll
    for (int n=0;n<2;n++) acc[m][n] = zero;
  #pragma unroll
  for (int k0=0;k0<128;k0+=32) {
    bf16x8 af[4], bfr[2];
    #pragma unroll
    for (int m=0;m<4;m++) {
      int row = wm*64 + m*16 + lr;
      unsigned addr = (unsigned)(row*256) + (((unsigned)(k0*2 + kg*16)) ^ (((unsigned)(row&7))<<4));
      af[m] = *reinterpret_cast<const bf16x8*>(lAc + addr);
    }
    #pragma unroll
    for (int n=0;n<2;n++) {
      int row = wn*32 + n*16 + lr;
      unsigned addr = (unsigned)(row*256) + (((unsigned)(k0*2 + kg*16)) ^ (((unsigned)(row&7))<<4));
      bfr[n] = *reinterpret_cast<const bf16x8*>(lBc + addr);
    }
    #pragma unroll
    for (int m=0;m<4;m++)
      #pragma unroll
      for (int n=0;n<2;n++)
        acc[m][n] = __builtin_amdgcn_mfma_f32_16x16x32_bf16(af[m], bfr[n], acc[m][n], 0, 0, 0);
  }
  // epilogue: +b1, relu, pooled2 partials (d-half disjoint per nh); z-half -> LDS -> coalesced
  const float* b1p = b1 + (size_t)bs*DD;
  float* p2row = p2part + (((size_t)(bs*4+mt)*2) + wm)*DD;
  __syncthreads();   // done reading lB
  #pragma unroll
  for (int n=0;n<2;n++) {
    int dl = wn*32 + n*16 + lr;
    int dg = nh*128 + dl;
    float bv = b1p[dg];
    float csum = 0.f;
    #pragma unroll
    for (int m=0;m<4;m++) {
      int rbase = wm*64 + m*16 + kg*4;
      #pragma unroll
      for (int j=0;j<4;j++) {
        float v = fmaxf(acc[m][n][j] + bv, 0.f);
        int row = rbase + j;
        unsigned addr = (unsigned)(row*256) + (((unsigned)(dl*2)) ^ (((unsigned)(row&7))<<4));
        *reinterpret_cast<unsigned short*>(lBc + addr) = f2bf(v);
        csum += v;
      }
    }
    csum += __shfl_xor(csum, 16);
    csum += __shfl_xor(csum, 32);
    if (kg == 0) p2row[dg] = csum;
  }
  __syncthreads();
  unsigned short* zb = zbf + (((size_t)b*CC + mt*128)*SS + s)*DD + nh*128;
  #pragma unroll
  for (int i=0;i<4;i++) {
    int flat = tid + i*512;
    int r = flat >> 4, ch = flat & 15;
    unsigned addr = (unsigned)(r*256) + (((unsigned)(ch*16)) ^ (((unsigned)(r&7))<<4));
    uint4 v = *reinterpret_cast<const uint4*>(lBc + addr);
    *reinterpret_cast<uint4*>(zb + (size_t)r*(SS*DD) + ch*8) = v;
  }
}

// ---- K4: route2 -> a2 (redundant per q), write w2out fp32 + w2bf + b2 quarter. grid 2048 ----
__global__ __launch_bounds__(256) void k4_route2(
    const float* __restrict__ p2part, const float* __restrict__ keys2,
    const float* __restrict__ Wp2, const float* __restrict__ bp2,
    float* __restrict__ w2out, unsigned short* __restrict__ w2bf,
    float* __restrict__ b2) {
  int bid = blockIdx.x;
  int bs = bid >> 2, q = bid & 3;
  int tid = threadIdx.x;
  __shared__ float a2s[PP];
  if (tid < 64) {
    float pv[4]; float ssq = 0.f;
    #pragma unroll
    for (int j=0;j<4;j++) {
      int d = tid + 64*j;
      float s8 = 0.f;
      #pragma unroll
      for (int r=0;r<8;r++) s8 += p2part[((size_t)bs*8 + r)*DD + d];
      pv[j] = s8 * (1.f/CC);
      ssq += pv[j]*pv[j];
    }
    #pragma unroll
    for (int off=32; off; off>>=1) ssq += __shfl_xor(ssq, off);
    float pn = sqrtf(ssq) + 1e-8f;
    float lg[PP];
    #pragma unroll
    for (int p=0;p<PP;p++) {
      float dot = 0.f, kn = 0.f;
      #pragma unroll
      for (int j=0;j<4;j++) {
        int d = tid + 64*j;
        float kv = keys2[p*DD + d];
        dot += pv[j]*kv; kn += kv*kv;
      }
      #pragma unroll
      for (int off=32; off; off>>=1) { dot += __shfl_xor(dot,off); kn += __shfl_xor(kn,off); }
      lg[p] = dot / (pn * (sqrtf(kn)+1e-8f));
    }
    if (tid == 0) {
      float mx = lg[0];
      #pragma unroll
      for (int p=1;p<PP;p++) mx = fmaxf(mx,lg[p]);
      float se=0.f, e[PP];
      #pragma unroll
      for (int p=0;p<PP;p++){ e[p]=__expf(lg[p]-mx); se+=e[p]; }
      float inv = 1.f/se;
      #pragma unroll
      for (int p=0;p<PP;p++) a2s[p]=e[p]*inv;
    }
  }
  __syncthreads();
  float a[PP];
  #pragma unroll
  for (int p=0;p<PP;p++) a[p]=a2s[p];
  #pragma unroll
  for (int i=0;i<8;i++) {
    int idx = tid + i*256;
    int tr = idx >> 6, c4 = idx & 63;
    size_t roff = (size_t)(q*32+tr)*DD + c4*4;
    size_t off = (size_t)bs*(TT*DD) + roff;
    float4 accv = make_float4(0.f,0.f,0.f,0.f);
    #pragma unroll
    for (int p=0;p<PP;p++) {
      float4 v = *reinterpret_cast<const float4*>(Wp2 + (size_t)p*(TT*DD) + roff);
      accv.x += a[p]*v.x; accv.y += a[p]*v.y; accv.z += a[p]*v.z; accv.w += a[p]*v.w;
    }
    *reinterpret_cast<float4*>(w2out + off) = accv;
    ushort4 o; o.x=f2bf(accv.x); o.y=f2bf(accv.y); o.z=f2bf(accv.z); o.w=f2bf(accv.w);
    *reinterpret_cast<ushort4*>(w2bf + off) = o;
  }
  if (tid < 32) {
    int t = q*32 + tid;
    float bacc = 0.f;
    #pragma unroll
    for (int p=0;p<PP;p++) bacc += a[p]*bp2[p*TT + t];
    b2[(size_t)bs*TT + t] = bacc;
  }
}

// ---- K5: GEMM2 out = x + Z @ W2^T + b2, K-split x2 pipelined. grid 2048, 512 thr, 64 KB LDS ----
__global__ __launch_bounds__(512, 4) void k5_gemm2(
    const unsigned short* __restrict__ zbf, const unsigned short* __restrict__ w2bf,
    const float* __restrict__ b2, const unsigned short* __restrict__ xbf,
    float* __restrict__ out) {
  int bid = blockIdx.x;
  int bs = bid >> 2, mt = bid & 3;
  int b = bs >> 6, s = bs & 63;
  __shared__ unsigned short lA[128*128];   // 32 KB, row 256 B, swizzled (z K-half)
  __shared__ unsigned short lB[128*128];   // 32 KB, row 256 B, swizzled (w2 K-half)
  int tid = threadIdx.x;
  char* lAc = reinterpret_cast<char*>(lA);
  char* lBc = reinterpret_cast<char*>(lB);
  const unsigned short* za = zbf + (((size_t)b*CC + mt*128)*SS + s)*DD;
  const unsigned short* wsrc = w2bf + (size_t)bs*(TT*DD);
  int r0 = tid >> 4, ch0 = tid & 15;      // per-thread tile coords (row from flat)
  // ---- stage kh=0 ----
  uint4 ta[4], tb[4];
  #pragma unroll
  for (int i=0;i<4;i++) {
    int flat = tid + i*512;
    int r = flat >> 4, ch = flat & 15;
    ta[i] = *reinterpret_cast<const uint4*>(za + (size_t)r*(SS*DD) + ch*8);
    tb[i] = *reinterpret_cast<const uint4*>(wsrc + (size_t)r*DD + ch*8);
  }
  #pragma unroll
  for (int i=0;i<4;i++) {
    int flat = tid + i*512;
    int r = flat >> 4, ch = flat & 15;
    unsigned addr = (unsigned)(r*256) + (((unsigned)(ch*16)) ^ (((unsigned)(r&7))<<4));
    *reinterpret_cast<uint4*>(lAc + addr) = ta[i];
    *reinterpret_cast<uint4*>(lBc + addr) = tb[i];
  }
  __syncthreads();
  // ---- issue kh=1 loads (overlap with kh=0 compute) ----
  uint4 ta2[4], tb2[4];
  #pragma unroll
  for (int i=0;i<4;i++) {
    int flat = tid + i*512;
    int r = flat >> 4, ch = flat & 15;
    ta2[i] = *reinterpret_cast<const uint4*>(za + (size_t)r*(SS*DD) + 128 + ch*8);
    tb2[i] = *reinterpret_cast<const uint4*>(wsrc + (size_t)r*DD + 128 + ch*8);
  }
  int wave = tid >> 6, lane = tid & 63;
  int wm = wave >> 2, wn = wave & 3;     // 2 x 4 waves, per-wave tile 64 x 32
  int lr = lane & 15, kg = lane >> 4;
  f32x4 zero = {0.f,0.f,0.f,0.f};
  f32x4 acc[4][2];
  #pragma unroll
  for (int m=0;m<4;m++)
    #pragma unroll
    for (int n=0;n<2;n++) acc[m][n] = zero;
  // ---- MFMA kh=0 ----
  #pragma unroll
  for (int k0=0;k0<128;k0+=32) {
    bf16x8 af[4], bfr[2];
    #pragma unroll
    for (int m=0;m<4;m++) {
      int row = wm*64 + m*16 + lr;
      unsigned addr = (unsigned)(row*256) + (((unsigned)(k0*2 + kg*16)) ^ (((unsigned)(row&7))<<4));
      af[m] = *reinterpret_cast<const bf16x8*>(lAc + addr);
    }
    #pragma unroll
    for (int n=0;n<2;n++) {
      int row = wn*32 + n*16 + lr;
      unsigned addr = (unsigned)(row*256) + (((unsigned)(k0*2 + kg*16)) ^ (((unsigned)(row&7))<<4));
      bfr[n] = *reinterpret_cast<const bf16x8*>(lBc + addr);
    }
    #pragma unroll
    for (int m=0;m<4;m++)
      #pragma unroll
      for (int n=0;n<2;n++)
        acc[m][n] = __builtin_amdgcn_mfma_f32_16x16x32_bf16(af[m], bfr[n], acc[m][n], 0, 0, 0);
  }
  __syncthreads();
  // ---- write kh=1 ----
  #pragma unroll
  for (int i=0;i<4;i++) {
    int flat = tid + i*512;
    int r = flat >> 4, ch = flat & 15;
    unsigned addr = (unsigned)(r*256) + (((unsigned)(ch*16)) ^ (((unsigned)(r&7))<<4));
    *reinterpret_cast<uint4*>(lAc + addr) = ta2[i];
    *reinterpret_cast<uint4*>(lBc + addr) = tb2[i];
  }
  __syncthreads();
  // ---- MFMA kh=1 ----
  #pragma unroll
  for (int k0=0;k0<128;k0+=32) {
    bf16x8 af[4], bfr[2];
    #pragma unroll
    for (int m=0;m<4;m++) {
      int row = wm*64 + m*16 + lr;
      unsigned addr = (unsigned)(row*256) + (((unsigned)(k0*2 + kg*16)) ^ (((unsigned)(row&7))<<4));
      af[m] = *reinterpret_cast<const bf16x8*>(lAc + addr);
    }
    #pragma unroll
    for (int n=0;n<2;n++) {
      int row = wn*32 + n*16 + lr;
      unsigned addr = (unsigned)(row*256) + (((unsigned)(k0*2 + kg*16)) ^ (((unsigned)(row&7))<<4));
      bfr[n] = *reinterpret_cast<const bf16x8*>(lBc + addr);
    }
    #pragma unroll
    for (int m=0;m<4;m++)
      #pragma unroll
      for (int n=0;n<2;n++)
        acc[m][n] = __builtin_amdgcn_mfma_f32_16x16x32_bf16(af[m], bfr[n], acc[m][n], 0, 0, 0);
  }
  (void)r0; (void)ch0;
  // ---- epilogue: +b2, residual, direct stores ----
  const float* b2p = b2 + (size_t)bs*TT;
  const unsigned short* xb = xbf + (((size_t)b*CC + mt*128)*SS + s)*TT;
  float* ob = out + (((size_t)b*CC + mt*128)*SS + s)*TT;
  #pragma unroll
  for (int n=0;n<2;n++) {
    int t = wn*32 + n*16 + lr;
    float bv = b2p[t];
    #pragma unroll
    for (int m=0;m<4;m++) {
      int rbase = wm*64 + m*16 + kg*4;
      #pragma unroll
      for (int j=0;j<4;j++) {
        size_t off = (size_t)(rbase+j)*(SS*TT) + t;
        ob[off] = acc[m][n][j] + bv + bf2f(xb[off]);
      }
    }
  }
}

extern "C" void kernel_launch(void* const* d_in, const int* in_sizes, int n_in,
                              void* d_out, int out_size, void* d_ws, size_t ws_size,
                              hipStream_t stream) {
  (void)in_sizes; (void)n_in; (void)out_size; (void)ws_size;
  const float* x     = (const float*)d_in[0];
  const float* gamma = (const float*)d_in[1];
  const float* beta  = (const float*)d_in[2];
  const float* keys1 = (const float*)d_in[3];
  const float* Wp1   = (const float*)d_in[4];
  const float* bp1   = (const float*)d_in[5];
  const float* keys2 = (const float*)d_in[6];
  const float* Wp2   = (const float*)d_in[7];
  const float* bp2   = (const float*)d_in[8];
  float* out = (float*)d_out;
  char* ws = (char*)d_ws;

  // ws layout (bytes):
  float* sumt        = (float*)(ws + 0);              // 512 B
  float* sumsq       = (float*)(ws + 512);            // 512 B
  float* csum_part   = (float*)(ws + 1024);           // 1 MB (128 x 2048, transposed)
  float* ssq_part    = (float*)(ws + 1049600);        // 1 MB
  float* p2part      = (float*)(ws + 2098176);        // 4 MB (512 x 8 x 256)
  float* b1          = (float*)(ws + 6292480);        // 512 KB
  float* b2          = (float*)(ws + 6816768);        // 256 KB
  unsigned short* w1bf = (unsigned short*)(ws + 7078912);   // 33.5 MB
  unsigned short* w2bf = (unsigned short*)(ws + 40633344);  // 33.5 MB
  unsigned short* xbf  = (unsigned short*)(ws + 74187776);  // 67 MB
  unsigned short* zbf  = (unsigned short*)(ws + 141296640); // 134 MB -> end ~275 MB

  float* w1out = out + 33554432;
  float* w2out = out + 50331648;

  k1_stats  <<<BS*4, 256, 0, stream>>>(x, csum_part, ssq_part, xbf);
  k1b_reduce<<<TT,   256, 0, stream>>>(csum_part, ssq_part, sumt, sumsq);
  k2_route1 <<<BS*4, 256, 0, stream>>>(sumt, sumsq, csum_part, gamma, beta, keys1, Wp1, bp1,
                                       w1out, w1bf, b1);
  k3_gemm1  <<<BS*8, 512, 0, stream>>>(xbf, sumt, sumsq, gamma, beta, w1bf, b1, zbf, p2part);
  k4_route2 <<<BS*4, 256, 0, stream>>>(p2part, keys2, Wp2, bp2, w2out, w2bf, b2);
  k5_gemm2  <<<BS*4, 512, 0, stream>>>(zbf, w2bf, b2, xbf, out);
}

// Round 8
// 310.753 us; speedup vs baseline: 1.1199x; 1.0962x over previous
//
#include <hip/hip_runtime.h>
#include <hip/hip_bf16.h>

#define BB 8
#define CC 512
#define SS 64
#define TT 128
#define DD 256
#define PP 8
#define BS (BB*SS)            // 512
#define NSTAT (BB*CC*SS)      // 262144
#define EPSV 1e-5f

typedef float f32x4 __attribute__((ext_vector_type(4)));
typedef __bf16 bf16x8 __attribute__((ext_vector_type(8)));

__device__ __forceinline__ unsigned short f2bf(float f) {
  unsigned u = __float_as_uint(f);
  u += 0x7FFFu + ((u >> 16) & 1u);
  return (unsigned short)(u >> 16);
}
__device__ __forceinline__ float bf2f(unsigned short h) {
  return __uint_as_float(((unsigned)h) << 16);
}

// ---- K1: per-block BN partials (transposed, no atomics) + bf16 stash of x. grid 2048 ----
__global__ __launch_bounds__(256) void k1_stats(const float* __restrict__ x,
    float* __restrict__ csum_part, float* __restrict__ ssq_part,
    unsigned short* __restrict__ xbf) {
  int bid = blockIdx.x;
  int bs = bid >> 2, cq = bid & 3;
  int b = bs >> 6, s = bs & 63;
  const float* xb = x + ((size_t)b * CC * SS + s) * TT;
  unsigned short* xo = xbf + ((size_t)b * CC * SS + s) * TT;
  int tid = threadIdx.x;
  int t4 = tid & 31, coff = tid >> 5;
  float cs0=0,cs1=0,cs2=0,cs3=0, ss0=0,ss1=0,ss2=0,ss3=0;
  #pragma unroll 8
  for (int k = 0; k < 16; k++) {
    int c = cq*128 + coff + k*8;
    float4 v = *reinterpret_cast<const float4*>(xb + (size_t)c*(SS*TT) + t4*4);
    ushort4 o; o.x=f2bf(v.x); o.y=f2bf(v.y); o.z=f2bf(v.z); o.w=f2bf(v.w);
    *reinterpret_cast<ushort4*>(xo + (size_t)c*(SS*TT) + t4*4) = o;
    cs0 += v.x; cs1 += v.y; cs2 += v.z; cs3 += v.w;
    ss0 += v.x*v.x; ss1 += v.y*v.y; ss2 += v.z*v.z; ss3 += v.w*v.w;
  }
  __shared__ float4 redC[256];
  __shared__ float4 redS[256];
  redC[tid] = make_float4(cs0,cs1,cs2,cs3);
  redS[tid] = make_float4(ss0,ss1,ss2,ss3);
  __syncthreads();
  if (tid < 32) {
    #pragma unroll
    for (int j = 1; j < 8; j++) {
      float4 a = redC[tid + j*32], bq = redS[tid + j*32];
      cs0+=a.x; cs1+=a.y; cs2+=a.z; cs3+=a.w;
      ss0+=bq.x; ss1+=bq.y; ss2+=bq.z; ss3+=bq.w;
    }
    int t0 = tid*4;
    csum_part[(size_t)(t0+0)*2048 + bid] = cs0;
    csum_part[(size_t)(t0+1)*2048 + bid] = cs1;
    csum_part[(size_t)(t0+2)*2048 + bid] = cs2;
    csum_part[(size_t)(t0+3)*2048 + bid] = cs3;
    ssq_part[(size_t)(t0+0)*2048 + bid] = ss0;
    ssq_part[(size_t)(t0+1)*2048 + bid] = ss1;
    ssq_part[(size_t)(t0+2)*2048 + bid] = ss2;
    ssq_part[(size_t)(t0+3)*2048 + bid] = ss3;
  }
}

// ---- K1b: reduce partials -> sumt/sumsq. grid 128 ----
__global__ __launch_bounds__(256) void k1b_reduce(
    const float* __restrict__ csum_part, const float* __restrict__ ssq_part,
    float* __restrict__ sumt, float* __restrict__ sumsq) {
  int t = blockIdx.x, tid = threadIdx.x;
  const float* cp = csum_part + (size_t)t*2048;
  const float* sp = ssq_part + (size_t)t*2048;
  float cs = 0.f, ss = 0.f;
  #pragma unroll
  for (int k=0;k<8;k++) { cs += cp[tid + k*256]; ss += sp[tid + k*256]; }
  #pragma unroll
  for (int off=32; off; off>>=1) { cs += __shfl_xor(cs,off); ss += __shfl_xor(ss,off); }
  __shared__ float redc[4], reds[4];
  int wave = tid >> 6, lane = tid & 63;
  if (lane == 0) { redc[wave] = cs; reds[wave] = ss; }
  __syncthreads();
  if (tid == 0) {
    sumt[t]  = redc[0]+redc[1]+redc[2]+redc[3];
    sumsq[t] = reds[0]+reds[1]+reds[2]+reds[3];
  }
}

// ---- K2: route1 -> a1 (redundant per q), write w1out fp32 + w1bf + b1 quarter. grid 2048 ----
__global__ __launch_bounds__(256) void k2_route1(
    const float* __restrict__ sumt, const float* __restrict__ sumsq,
    const float* __restrict__ csum_part, const float* __restrict__ gamma,
    const float* __restrict__ beta, const float* __restrict__ keys1,
    const float* __restrict__ Wp1, const float* __restrict__ bp1,
    float* __restrict__ w1out, unsigned short* __restrict__ w1bf,
    float* __restrict__ b1) {
  int bid = blockIdx.x;
  int bs = bid >> 2, q = bid & 3;
  int tid = threadIdx.x;
  __shared__ float a1s[PP];
  if (tid < 64) {
    float pv0, pv1;
    {
      int t = tid;
      float4 c4v = *reinterpret_cast<const float4*>(csum_part + (size_t)t*2048 + bs*4);
      float cs = c4v.x + c4v.y + c4v.z + c4v.w;
      float m = sumt[t] * (1.f/NSTAT);
      float var = sumsq[t]*(1.f/NSTAT) - m*m;
      float g = gamma[t] * rsqrtf(var + EPSV);
      pv0 = (cs*(1.f/CC) - m)*g + beta[t];
    }
    {
      int t = tid + 64;
      float4 c4v = *reinterpret_cast<const float4*>(csum_part + (size_t)t*2048 + bs*4);
      float cs = c4v.x + c4v.y + c4v.z + c4v.w;
      float m = sumt[t] * (1.f/NSTAT);
      float var = sumsq[t]*(1.f/NSTAT) - m*m;
      float g = gamma[t] * rsqrtf(var + EPSV);
      pv1 = (cs*(1.f/CC) - m)*g + beta[t];
    }
    float ssq = pv0*pv0 + pv1*pv1;
    #pragma unroll
    for (int off=32; off; off>>=1) ssq += __shfl_xor(ssq, off);
    float pn = sqrtf(ssq) + 1e-8f;
    float lg[PP];
    #pragma unroll
    for (int p=0;p<PP;p++) {
      float k0 = keys1[p*TT + tid], k1 = keys1[p*TT + tid + 64];
      float dot = pv0*k0 + pv1*k1;
      float kn = k0*k0 + k1*k1;
      #pragma unroll
      for (int off=32; off; off>>=1) { dot += __shfl_xor(dot,off); kn += __shfl_xor(kn,off); }
      lg[p] = dot / (pn * (sqrtf(kn) + 1e-8f));
    }
    if (tid == 0) {
      float mx = lg[0];
      #pragma unroll
      for (int p=1;p<PP;p++) mx = fmaxf(mx, lg[p]);
      float se = 0.f, e[PP];
      #pragma unroll
      for (int p=0;p<PP;p++){ e[p] = __expf(lg[p]-mx); se += e[p]; }
      float inv = 1.f/se;
      #pragma unroll
      for (int p=0;p<PP;p++) a1s[p] = e[p]*inv;
    }
  }
  __syncthreads();
  float a[PP];
  #pragma unroll
  for (int p=0;p<PP;p++) a[p]=a1s[p];
  #pragma unroll
  for (int i=0;i<8;i++) {
    int idx = tid + i*256;
    int dr = idx >> 5, c4 = idx & 31;
    size_t roff = (size_t)(q*64+dr)*TT + c4*4;
    size_t off = (size_t)bs*(DD*TT) + roff;
    float4 accv = make_float4(0.f,0.f,0.f,0.f);
    #pragma unroll
    for (int p=0;p<PP;p++) {
      float4 v = *reinterpret_cast<const float4*>(Wp1 + (size_t)p*(DD*TT) + roff);
      accv.x += a[p]*v.x; accv.y += a[p]*v.y; accv.z += a[p]*v.z; accv.w += a[p]*v.w;
    }
    *reinterpret_cast<float4*>(w1out + off) = accv;
    ushort4 o; o.x=f2bf(accv.x); o.y=f2bf(accv.y); o.z=f2bf(accv.z); o.w=f2bf(accv.w);
    *reinterpret_cast<ushort4*>(w1bf + off) = o;
  }
  if (tid < 64) {
    int d = q*64 + tid;
    float bacc = 0.f;
    #pragma unroll
    for (int p=0;p<PP;p++) bacc += a[p]*bp1[p*DD + d];
    b1[(size_t)bs*DD + d] = bacc;
  }
}

// ---- K3: GEMM1 Z = relu(BN(x) @ W1^T + b1), + pooled2 partials. grid 2048, 512 thr (R5) ----
__global__ __launch_bounds__(512) void k3_gemm1(
    const unsigned short* __restrict__ xbf, const float* __restrict__ sumt,
    const float* __restrict__ sumsq, const float* __restrict__ gamma,
    const float* __restrict__ beta, const unsigned short* __restrict__ w1bf,
    const float* __restrict__ b1, unsigned short* __restrict__ zbf,
    float* __restrict__ p2part) {
  int bid = blockIdx.x;
  int bs = bid >> 2, mt = bid & 3;
  int b = bs >> 6, s = bs & 63;
  __shared__ unsigned short lA[128*128];   // 32 KB, row 256 B, swizzled
  __shared__ unsigned short lB[256*128];   // 64 KB, row 256 B, swizzled; reused for z-tile
  __shared__ float mean_s[TT], g_s[TT], beta_s[TT];
  int tid = threadIdx.x;
  if (tid < TT) {
    float m = sumt[tid]*(1.f/NSTAT);
    float var = sumsq[tid]*(1.f/NSTAT) - m*m;
    mean_s[tid] = m;
    g_s[tid] = gamma[tid]*rsqrtf(var+EPSV);
    beta_s[tid] = beta[tid];
  }
  __syncthreads();
  char* lAc = reinterpret_cast<char*>(lA);
  char* lBc = reinterpret_cast<char*>(lB);
  auto bn2 = [&](unsigned pair, int t0) -> unsigned {
    float lo = bf2f((unsigned short)(pair & 0xFFFFu));
    float hi = bf2f((unsigned short)(pair >> 16));
    lo = (lo - mean_s[t0])*g_s[t0] + beta_s[t0];
    hi = (hi - mean_s[t0+1])*g_s[t0+1] + beta_s[t0+1];
    return ((unsigned)f2bf(hi) << 16) | (unsigned)f2bf(lo);
  };
  const unsigned short* xb = xbf + (((size_t)b*CC + mt*128)*SS + s)*TT;
  #pragma unroll
  for (int i=0;i<4;i++) {
    int flat = tid + i*512;
    int r = flat >> 4, c8 = flat & 15;
    int t0 = c8*8;
    uint4 v = *reinterpret_cast<const uint4*>(xb + (size_t)r*(SS*TT) + t0);
    uint4 o;
    o.x = bn2(v.x, t0); o.y = bn2(v.y, t0+2); o.z = bn2(v.z, t0+4); o.w = bn2(v.w, t0+6);
    unsigned addr = (unsigned)(r*256) + (((unsigned)(c8*16)) ^ (((unsigned)(r&7))<<4));
    *reinterpret_cast<uint4*>(lAc + addr) = o;
  }
  const unsigned short* wsrc = w1bf + (size_t)bs*(DD*TT);
  #pragma unroll
  for (int i=0;i<8;i++) {
    int flat = tid + i*512;
    int n = flat >> 4, ch = flat & 15;
    uint4 v = *reinterpret_cast<const uint4*>(wsrc + (size_t)flat*8);
    unsigned addr = (unsigned)(n*256) + (((unsigned)(ch*16)) ^ (((unsigned)(n&7))<<4));
    *reinterpret_cast<uint4*>(lBc + addr) = v;
  }
  __syncthreads();
  int wave = tid >> 6, lane = tid & 63;
  int wm = wave >> 2, wn = wave & 3;     // 2 x 4 waves, per-wave tile 64x64
  int lr = lane & 15, kg = lane >> 4;
  f32x4 zero = {0.f,0.f,0.f,0.f};
  f32x4 acc[4][4];
  #pragma unroll
  for (int m=0;m<4;m++)
    #pragma unroll
    for (int n=0;n<4;n++) acc[m][n] = zero;
  #pragma unroll
  for (int k0=0;k0<128;k0+=32) {
    bf16x8 af[4], bfr[4];
    #pragma unroll
    for (int m=0;m<4;m++) {
      int row = wm*64 + m*16 + lr;
      unsigned addr = (unsigned)(row*256) + (((unsigned)(k0*2 + kg*16)) ^ (((unsigned)(row&7))<<4));
      af[m] = *reinterpret_cast<const bf16x8*>(lAc + addr);
    }
    #pragma unroll
    for (int n=0;n<4;n++) {
      int row = wn*64 + n*16 + lr;
      unsigned addr = (unsigned)(row*256) + (((unsigned)(k0*2 + kg*16)) ^ (((unsigned)(row&7))<<4));
      bfr[n] = *reinterpret_cast<const bf16x8*>(lBc + addr);
    }
    #pragma unroll
    for (int m=0;m<4;m++)
      #pragma unroll
      for (int n=0;n<4;n++)
        acc[m][n] = __builtin_amdgcn_mfma_f32_16x16x32_bf16(af[m], bfr[n], acc[m][n], 0, 0, 0);
  }
  const float* b1p = b1 + (size_t)bs*DD;
  float* p2p = p2part + (((size_t)bid*2) + wm)*DD;
  __syncthreads();   // everyone done reading lB
  #pragma unroll
  for (int n=0;n<4;n++) {
    int d = wn*64 + n*16 + lr;
    float bv = b1p[d];
    float csum = 0.f;
    #pragma unroll
    for (int m=0;m<4;m++) {
      int rbase = wm*64 + m*16 + kg*4;
      #pragma unroll
      for (int j=0;j<4;j++) {
        float v = fmaxf(acc[m][n][j] + bv, 0.f);
        lB[(rbase+j)*DD + d] = f2bf(v);   // z-tile [128][256]
        csum += v;
      }
    }
    csum += __shfl_xor(csum, 16);
    csum += __shfl_xor(csum, 32);
    if (kg == 0) p2p[d] = csum;
  }
  __syncthreads();
  unsigned short* zb = zbf + (((size_t)b*CC + mt*128)*SS + s)*DD;
  #pragma unroll
  for (int i=0;i<8;i++) {
    int flat = tid + i*512;
    int r = flat >> 5, ch = flat & 31;
    uint4 v = *reinterpret_cast<const uint4*>(lBc + flat*16);
    *reinterpret_cast<uint4*>(zb + (size_t)r*(SS*DD) + ch*8) = v;
  }
}

// ---- K4: route2 -> a2 (redundant per q), write w2out fp32 + w2bf + b2 quarter. grid 2048 ----
__global__ __launch_bounds__(256) void k4_route2(
    const float* __restrict__ p2part, const float* __restrict__ keys2,
    const float* __restrict__ Wp2, const float* __restrict__ bp2,
    float* __restrict__ w2out, unsigned short* __restrict__ w2bf,
    float* __restrict__ b2) {
  int bid = blockIdx.x;
  int bs = bid >> 2, q = bid & 3;
  int tid = threadIdx.x;
  __shared__ float a2s[PP];
  if (tid < 64) {
    float pv[4]; float ssq = 0.f;
    #pragma unroll
    for (int j=0;j<4;j++) {
      int d = tid + 64*j;
      float s8 = 0.f;
      #pragma unroll
      for (int r=0;r<8;r++) s8 += p2part[((size_t)bs*8 + r)*DD + d];
      pv[j] = s8 * (1.f/CC);
      ssq += pv[j]*pv[j];
    }
    #pragma unroll
    for (int off=32; off; off>>=1) ssq += __shfl_xor(ssq, off);
    float pn = sqrtf(ssq) + 1e-8f;
    float lg[PP];
    #pragma unroll
    for (int p=0;p<PP;p++) {
      float dot = 0.f, kn = 0.f;
      #pragma unroll
      for (int j=0;j<4;j++) {
        int d = tid + 64*j;
        float kv = keys2[p*DD + d];
        dot += pv[j]*kv; kn += kv*kv;
      }
      #pragma unroll
      for (int off=32; off; off>>=1) { dot += __shfl_xor(dot,off); kn += __shfl_xor(kn,off); }
      lg[p] = dot / (pn * (sqrtf(kn)+1e-8f));
    }
    if (tid == 0) {
      float mx = lg[0];
      #pragma unroll
      for (int p=1;p<PP;p++) mx = fmaxf(mx,lg[p]);
      float se=0.f, e[PP];
      #pragma unroll
      for (int p=0;p<PP;p++){ e[p]=__expf(lg[p]-mx); se+=e[p]; }
      float inv = 1.f/se;
      #pragma unroll
      for (int p=0;p<PP;p++) a2s[p]=e[p]*inv;
    }
  }
  __syncthreads();
  float a[PP];
  #pragma unroll
  for (int p=0;p<PP;p++) a[p]=a2s[p];
  #pragma unroll
  for (int i=0;i<8;i++) {
    int idx = tid + i*256;
    int tr = idx >> 6, c4 = idx & 63;
    size_t roff = (size_t)(q*32+tr)*DD + c4*4;
    size_t off = (size_t)bs*(TT*DD) + roff;
    float4 accv = make_float4(0.f,0.f,0.f,0.f);
    #pragma unroll
    for (int p=0;p<PP;p++) {
      float4 v = *reinterpret_cast<const float4*>(Wp2 + (size_t)p*(TT*DD) + roff);
      accv.x += a[p]*v.x; accv.y += a[p]*v.y; accv.z += a[p]*v.z; accv.w += a[p]*v.w;
    }
    *reinterpret_cast<float4*>(w2out + off) = accv;
    ushort4 o; o.x=f2bf(accv.x); o.y=f2bf(accv.y); o.z=f2bf(accv.z); o.w=f2bf(accv.w);
    *reinterpret_cast<ushort4*>(w2bf + off) = o;
  }
  if (tid < 32) {
    int t = q*32 + tid;
    float bacc = 0.f;
    #pragma unroll
    for (int p=0;p<PP;p++) bacc += a[p]*bp2[p*TT + t];
    b2[(size_t)bs*TT + t] = bacc;
  }
}

// ---- K5: GEMM2 out = x + Z @ W2^T + b2. K-split x2, 64 KB LDS (2 blk/CU), coalesced epilogue ----
__global__ __launch_bounds__(512, 4) void k5_gemm2(
    const unsigned short* __restrict__ zbf, const unsigned short* __restrict__ w2bf,
    const float* __restrict__ b2, const unsigned short* __restrict__ xbf,
    float* __restrict__ out) {
  int bid = blockIdx.x;
  int bs = bid >> 2, mt = bid & 3;
  int b = bs >> 6, s = bs & 63;
  __shared__ __align__(16) char smem[65536];  // [0:32K) z K-half | [32K:64K) w2 K-half; epilogue: fp32 out-tile
  char* lAc = smem;
  char* lBc = smem + 32768;
  int tid = threadIdx.x;
  const unsigned short* za = zbf + (((size_t)b*CC + mt*128)*SS + s)*DD;
  const unsigned short* wsrc = w2bf + (size_t)bs*(TT*DD);
  // ---- stage kh=0 (K cols [0,128)) ----
  {
    uint4 ta[4], tb[4];
    #pragma unroll
    for (int i=0;i<4;i++) {
      int flat = tid + i*512;
      int r = flat >> 4, ch = flat & 15;
      ta[i] = *reinterpret_cast<const uint4*>(za + (size_t)r*(SS*DD) + ch*8);
      tb[i] = *reinterpret_cast<const uint4*>(wsrc + (size_t)r*DD + ch*8);
    }
    #pragma unroll
    for (int i=0;i<4;i++) {
      int flat = tid + i*512;
      int r = flat >> 4, ch = flat & 15;
      unsigned addr = (unsigned)(r*256) + (((unsigned)(ch*16)) ^ (((unsigned)(r&7))<<4));
      *reinterpret_cast<uint4*>(lAc + addr) = ta[i];
      *reinterpret_cast<uint4*>(lBc + addr) = tb[i];
    }
  }
  __syncthreads();
  // ---- prefetch kh=1 (K cols [128,256)) into registers (overlaps kh=0 MFMA) ----
  uint4 ta2[4], tb2[4];
  #pragma unroll
  for (int i=0;i<4;i++) {
    int flat = tid + i*512;
    int r = flat >> 4, ch = flat & 15;
    ta2[i] = *reinterpret_cast<const uint4*>(za + (size_t)r*(SS*DD) + 128 + ch*8);
    tb2[i] = *reinterpret_cast<const uint4*>(wsrc + (size_t)r*DD + 128 + ch*8);
  }
  int wave = tid >> 6, lane = tid & 63;
  int wm = wave >> 2, wn = wave & 3;     // 2 x 4 waves, per-wave tile 64 x 32
  int lr = lane & 15, kg = lane >> 4;
  f32x4 zero = {0.f,0.f,0.f,0.f};
  f32x4 acc[4][2];
  #pragma unroll
  for (int m=0;m<4;m++)
    #pragma unroll
    for (int n=0;n<2;n++) acc[m][n] = zero;
  // ---- MFMA kh=0 ----
  #pragma unroll
  for (int k0=0;k0<128;k0+=32) {
    bf16x8 af[4], bfr[2];
    #pragma unroll
    for (int m=0;m<4;m++) {
      int row = wm*64 + m*16 + lr;
      unsigned addr = (unsigned)(row*256) + (((unsigned)(k0*2 + kg*16)) ^ (((unsigned)(row&7))<<4));
      af[m] = *reinterpret_cast<const bf16x8*>(lAc + addr);
    }
    #pragma unroll
    for (int n=0;n<2;n++) {
      int row = wn*32 + n*16 + lr;
      unsigned addr = (unsigned)(row*256) + (((unsigned)(k0*2 + kg*16)) ^ (((unsigned)(row&7))<<4));
      bfr[n] = *reinterpret_cast<const bf16x8*>(lBc + addr);
    }
    #pragma unroll
    for (int m=0;m<4;m++)
      #pragma unroll
      for (int n=0;n<2;n++)
        acc[m][n] = __builtin_amdgcn_mfma_f32_16x16x32_bf16(af[m], bfr[n], acc[m][n], 0, 0, 0);
  }
  __syncthreads();
  // ---- write kh=1 tiles ----
  #pragma unroll
  for (int i=0;i<4;i++) {
    int flat = tid + i*512;
    int r = flat >> 4, ch = flat & 15;
    unsigned addr = (unsigned)(r*256) + (((unsigned)(ch*16)) ^ (((unsigned)(r&7))<<4));
    *reinterpret_cast<uint4*>(lAc + addr) = ta2[i];
    *reinterpret_cast<uint4*>(lBc + addr) = tb2[i];
  }
  __syncthreads();
  // ---- MFMA kh=1 (accumulates into same acc) ----
  #pragma unroll
  for (int k0=0;k0<128;k0+=32) {
    bf16x8 af[4], bfr[2];
    #pragma unroll
    for (int m=0;m<4;m++) {
      int row = wm*64 + m*16 + lr;
      unsigned addr = (unsigned)(row*256) + (((unsigned)(k0*2 + kg*16)) ^ (((unsigned)(row&7))<<4));
      af[m] = *reinterpret_cast<const bf16x8*>(lAc + addr);
    }
    #pragma unroll
    for (int n=0;n<2;n++) {
      int row = wn*32 + n*16 + lr;
      unsigned addr = (unsigned)(row*256) + (((unsigned)(k0*2 + kg*16)) ^ (((unsigned)(row&7))<<4));
      bfr[n] = *reinterpret_cast<const bf16x8*>(lBc + addr);
    }
    #pragma unroll
    for (int m=0;m<4;m++)
      #pragma unroll
      for (int n=0;n<2;n++)
        acc[m][n] = __builtin_amdgcn_mfma_f32_16x16x32_bf16(af[m], bfr[n], acc[m][n], 0, 0, 0);
  }
  __syncthreads();
  // ---- epilogue: +b2 -> fp32 out-tile [128][128] over whole smem (swizzled) ----
  const float* b2p = b2 + (size_t)bs*TT;
  #pragma unroll
  for (int n=0;n<2;n++) {
    int t = wn*32 + n*16 + lr;
    float bv = b2p[t];
    #pragma unroll
    for (int m=0;m<4;m++) {
      int rbase = wm*64 + m*16 + kg*4;
      #pragma unroll
      for (int j=0;j<4;j++) {
        int row = rbase + j;
        unsigned addr = (unsigned)(row*512) + (((unsigned)(t*4)) ^ (((unsigned)(row&7))<<4));
        *reinterpret_cast<float*>(smem + addr) = acc[m][n][j] + bv;
      }
    }
  }
  __syncthreads();
  // ---- residual + coalesced float4 stores ----
  const unsigned short* xb = xbf + (((size_t)b*CC + mt*128)*SS + s)*TT;
  float* ob = out + (((size_t)b*CC + mt*128)*SS + s)*TT;
  #pragma unroll
  for (int i=0;i<8;i++) {
    int flat = tid + i*512;
    int r = flat >> 5, c4 = flat & 31;
    unsigned addr = (unsigned)(r*512) + (((unsigned)(c4*16)) ^ (((unsigned)(r&7))<<4));
    float4 v = *reinterpret_cast<const float4*>(smem + addr);
    ushort4 xv = *reinterpret_cast<const ushort4*>(xb + (size_t)r*(SS*TT) + c4*4);
    v.x += bf2f(xv.x); v.y += bf2f(xv.y); v.z += bf2f(xv.z); v.w += bf2f(xv.w);
    *reinterpret_cast<float4*>(ob + (size_t)r*(SS*TT) + c4*4) = v;
  }
}

extern "C" void kernel_launch(void* const* d_in, const int* in_sizes, int n_in,
                              void* d_out, int out_size, void* d_ws, size_t ws_size,
                              hipStream_t stream) {
  (void)in_sizes; (void)n_in; (void)out_size; (void)ws_size;
  const float* x     = (const float*)d_in[0];
  const float* gamma = (const float*)d_in[1];
  const float* beta  = (const float*)d_in[2];
  const float* keys1 = (const float*)d_in[3];
  const float* Wp1   = (const float*)d_in[4];
  const float* bp1   = (const float*)d_in[5];
  const float* keys2 = (const float*)d_in[6];
  const float* Wp2   = (const float*)d_in[7];
  const float* bp2   = (const float*)d_in[8];
  float* out = (float*)d_out;
  char* ws = (char*)d_ws;

  // ws layout (bytes):
  float* sumt        = (float*)(ws + 0);              // 512 B
  float* sumsq       = (float*)(ws + 512);            // 512 B
  float* csum_part   = (float*)(ws + 1024);           // 1 MB (128 x 2048, transposed)
  float* ssq_part    = (float*)(ws + 1049600);        // 1 MB
  float* p2part      = (float*)(ws + 2098176);        // 4 MB (512 x 8 x 256)
  float* b1          = (float*)(ws + 6292480);        // 512 KB
  float* b2          = (float*)(ws + 6816768);        // 256 KB
  unsigned short* w1bf = (unsigned short*)(ws + 7078912);   // 33.5 MB
  unsigned short* w2bf = (unsigned short*)(ws + 40633344);  // 33.5 MB
  unsigned short* xbf  = (unsigned short*)(ws + 74187776);  // 67 MB
  unsigned short* zbf  = (unsigned short*)(ws + 141296640); // 134 MB -> end ~275 MB

  float* w1out = out + 33554432;
  float* w2out = out + 50331648;

  k1_stats  <<<BS*4, 256, 0, stream>>>(x, csum_part, ssq_part, xbf);
  k1b_reduce<<<TT,   256, 0, stream>>>(csum_part, ssq_part, sumt, sumsq);
  k2_route1 <<<BS*4, 256, 0, stream>>>(sumt, sumsq, csum_part, gamma, beta, keys1, Wp1, bp1,
                                       w1out, w1bf, b1);
  k3_gemm1  <<<BS*4, 512, 0, stream>>>(xbf, sumt, sumsq, gamma, beta, w1bf, b1, zbf, p2part);
  k4_route2 <<<BS*4, 256, 0, stream>>>(p2part, keys2, Wp2, bp2, w2out, w2bf, b2);
  k5_gemm2  <<<BS*4, 512, 0, stream>>>(zbf, w2bf, b2, xbf, out);
}

// Round 9
// 293.937 us; speedup vs baseline: 1.1840x; 1.0572x over previous
//
#include <hip/hip_runtime.h>
#include <hip/hip_bf16.h>

#define BB 8
#define CC 512
#define SS 64
#define TT 128
#define DD 256
#define PP 8
#define BS (BB*SS)            // 512
#define NSTAT (BB*CC*SS)      // 262144
#define EPSV 1e-5f

typedef float f32x4 __attribute__((ext_vector_type(4)));
typedef __bf16 bf16x8 __attribute__((ext_vector_type(8)));

__device__ __forceinline__ unsigned short f2bf(float f) {
  unsigned u = __float_as_uint(f);
  u += 0x7FFFu + ((u >> 16) & 1u);
  return (unsigned short)(u >> 16);
}
__device__ __forceinline__ float bf2f(unsigned short h) {
  return __uint_as_float(((unsigned)h) << 16);
}

// ---- K1: per-block BN partials (transposed, no atomics) + bf16 stash of x. grid 2048 ----
__global__ __launch_bounds__(256) void k1_stats(const float* __restrict__ x,
    float* __restrict__ csum_part, float* __restrict__ ssq_part,
    unsigned short* __restrict__ xbf) {
  int bid = blockIdx.x;
  int bs = bid >> 2, cq = bid & 3;
  int b = bs >> 6, s = bs & 63;
  const float* xb = x + ((size_t)b * CC * SS + s) * TT;
  unsigned short* xo = xbf + ((size_t)b * CC * SS + s) * TT;
  int tid = threadIdx.x;
  int t4 = tid & 31, coff = tid >> 5;
  float cs0=0,cs1=0,cs2=0,cs3=0, ss0=0,ss1=0,ss2=0,ss3=0;
  #pragma unroll 8
  for (int k = 0; k < 16; k++) {
    int c = cq*128 + coff + k*8;
    float4 v = *reinterpret_cast<const float4*>(xb + (size_t)c*(SS*TT) + t4*4);
    ushort4 o; o.x=f2bf(v.x); o.y=f2bf(v.y); o.z=f2bf(v.z); o.w=f2bf(v.w);
    *reinterpret_cast<ushort4*>(xo + (size_t)c*(SS*TT) + t4*4) = o;
    cs0 += v.x; cs1 += v.y; cs2 += v.z; cs3 += v.w;
    ss0 += v.x*v.x; ss1 += v.y*v.y; ss2 += v.z*v.z; ss3 += v.w*v.w;
  }
  __shared__ float4 redC[256];
  __shared__ float4 redS[256];
  redC[tid] = make_float4(cs0,cs1,cs2,cs3);
  redS[tid] = make_float4(ss0,ss1,ss2,ss3);
  __syncthreads();
  if (tid < 32) {
    #pragma unroll
    for (int j = 1; j < 8; j++) {
      float4 a = redC[tid + j*32], bq = redS[tid + j*32];
      cs0+=a.x; cs1+=a.y; cs2+=a.z; cs3+=a.w;
      ss0+=bq.x; ss1+=bq.y; ss2+=bq.z; ss3+=bq.w;
    }
    int t0 = tid*4;
    csum_part[(size_t)(t0+0)*2048 + bid] = cs0;
    csum_part[(size_t)(t0+1)*2048 + bid] = cs1;
    csum_part[(size_t)(t0+2)*2048 + bid] = cs2;
    csum_part[(size_t)(t0+3)*2048 + bid] = cs3;
    ssq_part[(size_t)(t0+0)*2048 + bid] = ss0;
    ssq_part[(size_t)(t0+1)*2048 + bid] = ss1;
    ssq_part[(size_t)(t0+2)*2048 + bid] = ss2;
    ssq_part[(size_t)(t0+3)*2048 + bid] = ss3;
  }
}

// ---- K1b: reduce partials -> sumt/sumsq. grid 128 ----
__global__ __launch_bounds__(256) void k1b_reduce(
    const float* __restrict__ csum_part, const float* __restrict__ ssq_part,
    float* __restrict__ sumt, float* __restrict__ sumsq) {
  int t = blockIdx.x, tid = threadIdx.x;
  const float* cp = csum_part + (size_t)t*2048;
  const float* sp = ssq_part + (size_t)t*2048;
  float cs = 0.f, ss = 0.f;
  #pragma unroll
  for (int k=0;k<8;k++) { cs += cp[tid + k*256]; ss += sp[tid + k*256]; }
  #pragma unroll
  for (int off=32; off; off>>=1) { cs += __shfl_xor(cs,off); ss += __shfl_xor(ss,off); }
  __shared__ float redc[4], reds[4];
  int wave = tid >> 6, lane = tid & 63;
  if (lane == 0) { redc[wave] = cs; reds[wave] = ss; }
  __syncthreads();
  if (tid == 0) {
    sumt[t]  = redc[0]+redc[1]+redc[2]+redc[3];
    sumsq[t] = reds[0]+reds[1]+reds[2]+reds[3];
  }
}

// ---- K2: route1 -> w1out fp32 (unscaled) + w1bf = g*w1 (BN folded) + b1' quarter. grid 2048 ----
__global__ __launch_bounds__(256) void k2_route1(
    const float* __restrict__ sumt, const float* __restrict__ sumsq,
    const float* __restrict__ csum_part, const float* __restrict__ gamma,
    const float* __restrict__ beta, const float* __restrict__ keys1,
    const float* __restrict__ Wp1, const float* __restrict__ bp1,
    float* __restrict__ w1out, unsigned short* __restrict__ w1bf,
    float* __restrict__ b1) {
  int bid = blockIdx.x;
  int bs = bid >> 2, q = bid & 3;
  int tid = threadIdx.x;
  __shared__ float a1s[PP];
  __shared__ float g_s[TT], h_s[TT];
  __shared__ float db_s[64];
  if (tid < TT) {
    float m = sumt[tid] * (1.f/NSTAT);
    float var = sumsq[tid]*(1.f/NSTAT) - m*m;
    float g = gamma[tid] * rsqrtf(var + EPSV);
    g_s[tid] = g;
    h_s[tid] = beta[tid] - m*g;   // y = x*g + h
  }
  if (tid < 64) {
    float pv0, pv1;
    {
      int t = tid;
      float4 c4v = *reinterpret_cast<const float4*>(csum_part + (size_t)t*2048 + bs*4);
      float cs = c4v.x + c4v.y + c4v.z + c4v.w;
      float m = sumt[t] * (1.f/NSTAT);
      float var = sumsq[t]*(1.f/NSTAT) - m*m;
      float g = gamma[t] * rsqrtf(var + EPSV);
      pv0 = (cs*(1.f/CC) - m)*g + beta[t];
    }
    {
      int t = tid + 64;
      float4 c4v = *reinterpret_cast<const float4*>(csum_part + (size_t)t*2048 + bs*4);
      float cs = c4v.x + c4v.y + c4v.z + c4v.w;
      float m = sumt[t] * (1.f/NSTAT);
      float var = sumsq[t]*(1.f/NSTAT) - m*m;
      float g = gamma[t] * rsqrtf(var + EPSV);
      pv1 = (cs*(1.f/CC) - m)*g + beta[t];
    }
    float ssq = pv0*pv0 + pv1*pv1;
    #pragma unroll
    for (int off=32; off; off>>=1) ssq += __shfl_xor(ssq, off);
    float pn = sqrtf(ssq) + 1e-8f;
    float lg[PP];
    #pragma unroll
    for (int p=0;p<PP;p++) {
      float k0 = keys1[p*TT + tid], k1 = keys1[p*TT + tid + 64];
      float dot = pv0*k0 + pv1*k1;
      float kn = k0*k0 + k1*k1;
      #pragma unroll
      for (int off=32; off; off>>=1) { dot += __shfl_xor(dot,off); kn += __shfl_xor(kn,off); }
      lg[p] = dot / (pn * (sqrtf(kn) + 1e-8f));
    }
    if (tid == 0) {
      float mx = lg[0];
      #pragma unroll
      for (int p=1;p<PP;p++) mx = fmaxf(mx, lg[p]);
      float se = 0.f, e[PP];
      #pragma unroll
      for (int p=0;p<PP;p++){ e[p] = __expf(lg[p]-mx); se += e[p]; }
      float inv = 1.f/se;
      #pragma unroll
      for (int p=0;p<PP;p++) a1s[p] = e[p]*inv;
    }
  }
  __syncthreads();
  float a[PP];
  #pragma unroll
  for (int p=0;p<PP;p++) a[p]=a1s[p];
  #pragma unroll
  for (int i=0;i<8;i++) {
    int idx = tid + i*256;
    int dr = idx >> 5, c4 = idx & 31;
    size_t roff = (size_t)(q*64+dr)*TT + c4*4;
    size_t off = (size_t)bs*(DD*TT) + roff;
    float4 accv = make_float4(0.f,0.f,0.f,0.f);
    #pragma unroll
    for (int p=0;p<PP;p++) {
      float4 v = *reinterpret_cast<const float4*>(Wp1 + (size_t)p*(DD*TT) + roff);
      accv.x += a[p]*v.x; accv.y += a[p]*v.y; accv.z += a[p]*v.z; accv.w += a[p]*v.w;
    }
    *reinterpret_cast<float4*>(w1out + off) = accv;        // unscaled (reference output)
    float4 gv = *reinterpret_cast<const float4*>(g_s + c4*4);
    ushort4 o;
    o.x=f2bf(accv.x*gv.x); o.y=f2bf(accv.y*gv.y);
    o.z=f2bf(accv.z*gv.z); o.w=f2bf(accv.w*gv.w);
    *reinterpret_cast<ushort4*>(w1bf + off) = o;           // BN-folded shadow
    float4 hv = *reinterpret_cast<const float4*>(h_s + c4*4);
    float pd = accv.x*hv.x + accv.y*hv.y + accv.z*hv.z + accv.w*hv.w;
    #pragma unroll
    for (int off2=16; off2; off2>>=1) pd += __shfl_xor(pd, off2);
    if (c4 == 0) db_s[dr] = pd;                            // Σ_t h[t]*w1[d,t]
  }
  __syncthreads();
  if (tid < 64) {
    int d = q*64 + tid;
    float bacc = db_s[tid];
    #pragma unroll
    for (int p=0;p<PP;p++) bacc += a[p]*bp1[p*DD + d];
    b1[(size_t)bs*DD + d] = bacc;                          // b1' (BN bias folded)
  }
}

// ---- K3: GEMM1 Z = relu(xbf @ (g*W1)^T + b1') + pooled2 partials. grid 2048, 512 thr ----
__global__ __launch_bounds__(512) void k3_gemm1(
    const unsigned short* __restrict__ xbf, const unsigned short* __restrict__ w1bf,
    const float* __restrict__ b1, unsigned short* __restrict__ zbf,
    float* __restrict__ p2part) {
  int bid = blockIdx.x;
  int bs = bid >> 2, mt = bid & 3;
  int b = bs >> 6, s = bs & 63;
  __shared__ unsigned short lA[128*128];   // 32 KB, row 256 B, swizzled
  __shared__ unsigned short lB[256*128];   // 64 KB, row 256 B, swizzled; reused for z-tile
  int tid = threadIdx.x;
  char* lAc = reinterpret_cast<char*>(lA);
  char* lBc = reinterpret_cast<char*>(lB);
  // stage A: pure swizzled copy (BN folded into weights)
  const unsigned short* xb = xbf + (((size_t)b*CC + mt*128)*SS + s)*TT;
  #pragma unroll
  for (int i=0;i<4;i++) {
    int flat = tid + i*512;
    int r = flat >> 4, c8 = flat & 15;
    uint4 v = *reinterpret_cast<const uint4*>(xb + (size_t)r*(SS*TT) + c8*8);
    unsigned addr = (unsigned)(r*256) + (((unsigned)(c8*16)) ^ (((unsigned)(r&7))<<4));
    *reinterpret_cast<uint4*>(lAc + addr) = v;
  }
  const unsigned short* wsrc = w1bf + (size_t)bs*(DD*TT);
  #pragma unroll
  for (int i=0;i<8;i++) {
    int flat = tid + i*512;
    int n = flat >> 4, ch = flat & 15;
    uint4 v = *reinterpret_cast<const uint4*>(wsrc + (size_t)flat*8);
    unsigned addr = (unsigned)(n*256) + (((unsigned)(ch*16)) ^ (((unsigned)(n&7))<<4));
    *reinterpret_cast<uint4*>(lBc + addr) = v;
  }
  __syncthreads();
  int wave = tid >> 6, lane = tid & 63;
  int wm = wave >> 2, wn = wave & 3;     // 2 x 4 waves, per-wave tile 64x64
  int lr = lane & 15, kg = lane >> 4;
  f32x4 zero = {0.f,0.f,0.f,0.f};
  f32x4 acc[4][4];
  #pragma unroll
  for (int m=0;m<4;m++)
    #pragma unroll
    for (int n=0;n<4;n++) acc[m][n] = zero;
  #pragma unroll
  for (int k0=0;k0<128;k0+=32) {
    bf16x8 af[4], bfr[4];
    #pragma unroll
    for (int m=0;m<4;m++) {
      int row = wm*64 + m*16 + lr;
      unsigned addr = (unsigned)(row*256) + (((unsigned)(k0*2 + kg*16)) ^ (((unsigned)(row&7))<<4));
      af[m] = *reinterpret_cast<const bf16x8*>(lAc + addr);
    }
    #pragma unroll
    for (int n=0;n<4;n++) {
      int row = wn*64 + n*16 + lr;
      unsigned addr = (unsigned)(row*256) + (((unsigned)(k0*2 + kg*16)) ^ (((unsigned)(row&7))<<4));
      bfr[n] = *reinterpret_cast<const bf16x8*>(lBc + addr);
    }
    #pragma unroll
    for (int m=0;m<4;m++)
      #pragma unroll
      for (int n=0;n<4;n++)
        acc[m][n] = __builtin_amdgcn_mfma_f32_16x16x32_bf16(af[m], bfr[n], acc[m][n], 0, 0, 0);
  }
  const float* b1p = b1 + (size_t)bs*DD;
  float* p2p = p2part + (((size_t)bid*2) + wm)*DD;
  __syncthreads();   // everyone done reading lB
  #pragma unroll
  for (int n=0;n<4;n++) {
    int d = wn*64 + n*16 + lr;
    float bv = b1p[d];
    float csum = 0.f;
    #pragma unroll
    for (int m=0;m<4;m++) {
      int rbase = wm*64 + m*16 + kg*4;
      #pragma unroll
      for (int j=0;j<4;j++) {
        float v = fmaxf(acc[m][n][j] + bv, 0.f);
        lB[(rbase+j)*DD + d] = f2bf(v);   // z-tile [128][256]
        csum += v;
      }
    }
    csum += __shfl_xor(csum, 16);
    csum += __shfl_xor(csum, 32);
    if (kg == 0) p2p[d] = csum;
  }
  __syncthreads();
  unsigned short* zb = zbf + (((size_t)b*CC + mt*128)*SS + s)*DD;
  #pragma unroll
  for (int i=0;i<8;i++) {
    int flat = tid + i*512;
    int r = flat >> 5, ch = flat & 31;
    uint4 v = *reinterpret_cast<const uint4*>(lBc + flat*16);
    *reinterpret_cast<uint4*>(zb + (size_t)r*(SS*DD) + ch*8) = v;
  }
}

// ---- K4: route2 -> a2 (redundant per q), write w2out fp32 + w2bf + b2 quarter. grid 2048 ----
__global__ __launch_bounds__(256) void k4_route2(
    const float* __restrict__ p2part, const float* __restrict__ keys2,
    const float* __restrict__ Wp2, const float* __restrict__ bp2,
    float* __restrict__ w2out, unsigned short* __restrict__ w2bf,
    float* __restrict__ b2) {
  int bid = blockIdx.x;
  int bs = bid >> 2, q = bid & 3;
  int tid = threadIdx.x;
  __shared__ float a2s[PP];
  if (tid < 64) {
    float pv[4]; float ssq = 0.f;
    #pragma unroll
    for (int j=0;j<4;j++) {
      int d = tid + 64*j;
      float s8 = 0.f;
      #pragma unroll
      for (int r=0;r<8;r++) s8 += p2part[((size_t)bs*8 + r)*DD + d];
      pv[j] = s8 * (1.f/CC);
      ssq += pv[j]*pv[j];
    }
    #pragma unroll
    for (int off=32; off; off>>=1) ssq += __shfl_xor(ssq, off);
    float pn = sqrtf(ssq) + 1e-8f;
    float lg[PP];
    #pragma unroll
    for (int p=0;p<PP;p++) {
      float dot = 0.f, kn = 0.f;
      #pragma unroll
      for (int j=0;j<4;j++) {
        int d = tid + 64*j;
        float kv = keys2[p*DD + d];
        dot += pv[j]*kv; kn += kv*kv;
      }
      #pragma unroll
      for (int off=32; off; off>>=1) { dot += __shfl_xor(dot,off); kn += __shfl_xor(kn,off); }
      lg[p] = dot / (pn * (sqrtf(kn)+1e-8f));
    }
    if (tid == 0) {
      float mx = lg[0];
      #pragma unroll
      for (int p=1;p<PP;p++) mx = fmaxf(mx,lg[p]);
      float se=0.f, e[PP];
      #pragma unroll
      for (int p=0;p<PP;p++){ e[p]=__expf(lg[p]-mx); se+=e[p]; }
      float inv = 1.f/se;
      #pragma unroll
      for (int p=0;p<PP;p++) a2s[p]=e[p]*inv;
    }
  }
  __syncthreads();
  float a[PP];
  #pragma unroll
  for (int p=0;p<PP;p++) a[p]=a2s[p];
  #pragma unroll
  for (int i=0;i<8;i++) {
    int idx = tid + i*256;
    int tr = idx >> 6, c4 = idx & 63;
    size_t roff = (size_t)(q*32+tr)*DD + c4*4;
    size_t off = (size_t)bs*(TT*DD) + roff;
    float4 accv = make_float4(0.f,0.f,0.f,0.f);
    #pragma unroll
    for (int p=0;p<PP;p++) {
      float4 v = *reinterpret_cast<const float4*>(Wp2 + (size_t)p*(TT*DD) + roff);
      accv.x += a[p]*v.x; accv.y += a[p]*v.y; accv.z += a[p]*v.z; accv.w += a[p]*v.w;
    }
    *reinterpret_cast<float4*>(w2out + off) = accv;
    ushort4 o; o.x=f2bf(accv.x); o.y=f2bf(accv.y); o.z=f2bf(accv.z); o.w=f2bf(accv.w);
    *reinterpret_cast<ushort4*>(w2bf + off) = o;
  }
  if (tid < 32) {
    int t = q*32 + tid;
    float bacc = 0.f;
    #pragma unroll
    for (int p=0;p<PP;p++) bacc += a[p]*bp2[p*TT + t];
    b2[(size_t)bs*TT + t] = bacc;
  }
}

// ---- K5: GEMM2 out = x + Z @ W2^T + b2. grid 2048, 1024 thr, 128 KB LDS, 16 waves/CU ----
__global__ __launch_bounds__(1024, 4) void k5_gemm2(
    const unsigned short* __restrict__ zbf, const unsigned short* __restrict__ w2bf,
    const float* __restrict__ b2, const unsigned short* __restrict__ xbf,
    float* __restrict__ out) {
  int bid = blockIdx.x;
  int bs = bid >> 2, mt = bid & 3;
  int b = bs >> 6, s = bs & 63;
  __shared__ unsigned short lA[128*256];   // 64 KB, row 512 B, swizzled
  __shared__ unsigned short lB[128*256];   // 64 KB, row 512 B, swizzled
  int tid = threadIdx.x;
  char* lAc = reinterpret_cast<char*>(lA);
  char* lBc = reinterpret_cast<char*>(lB);
  const unsigned short* za = zbf + (((size_t)b*CC + mt*128)*SS + s)*DD;
  #pragma unroll
  for (int i=0;i<4;i++) {
    int flat = tid + i*1024;
    int r = flat >> 5, ch = flat & 31;
    uint4 v = *reinterpret_cast<const uint4*>(za + (size_t)r*(SS*DD) + ch*8);
    unsigned addr = (unsigned)(r*512) + (((unsigned)(ch*16)) ^ (((unsigned)(r&7))<<4));
    *reinterpret_cast<uint4*>(lAc + addr) = v;
  }
  const unsigned short* wsrc = w2bf + (size_t)bs*(TT*DD);
  #pragma unroll
  for (int i=0;i<4;i++) {
    int flat = tid + i*1024;
    int r = flat >> 5, ch = flat & 31;
    uint4 v = *reinterpret_cast<const uint4*>(wsrc + (size_t)flat*8);
    unsigned addr = (unsigned)(r*512) + (((unsigned)(ch*16)) ^ (((unsigned)(r&7))<<4));
    *reinterpret_cast<uint4*>(lBc + addr) = v;
  }
  __syncthreads();
  int wave = tid >> 6, lane = tid & 63;
  int wm = wave >> 2, wn = wave & 3;     // 4 x 4 waves, per-wave tile 32 x 32
  int lr = lane & 15, kg = lane >> 4;
  f32x4 zero = {0.f,0.f,0.f,0.f};
  f32x4 acc[2][2];
  #pragma unroll
  for (int m=0;m<2;m++)
    #pragma unroll
    for (int n=0;n<2;n++) acc[m][n] = zero;
  #pragma unroll
  for (int k0=0;k0<256;k0+=32) {
    bf16x8 af[2], bfr[2];
    #pragma unroll
    for (int m=0;m<2;m++) {
      int row = wm*32 + m*16 + lr;
      unsigned addr = (unsigned)(row*512) + (((unsigned)(k0*2 + kg*16)) ^ (((unsigned)(row&7))<<4));
      af[m] = *reinterpret_cast<const bf16x8*>(lAc + addr);
    }
    #pragma unroll
    for (int n=0;n<2;n++) {
      int row = wn*32 + n*16 + lr;
      unsigned addr = (unsigned)(row*512) + (((unsigned)(k0*2 + kg*16)) ^ (((unsigned)(row&7))<<4));
      bfr[n] = *reinterpret_cast<const bf16x8*>(lBc + addr);
    }
    #pragma unroll
    for (int m=0;m<2;m++)
      #pragma unroll
      for (int n=0;n<2;n++)
        acc[m][n] = __builtin_amdgcn_mfma_f32_16x16x32_bf16(af[m], bfr[n], acc[m][n], 0, 0, 0);
  }
  const float* b2p = b2 + (size_t)bs*TT;
  const unsigned short* xb = xbf + (((size_t)b*CC + mt*128)*SS + s)*TT;
  float* ob = out + (((size_t)b*CC + mt*128)*SS + s)*TT;
  #pragma unroll
  for (int n=0;n<2;n++) {
    int t = wn*32 + n*16 + lr;
    float bv = b2p[t];
    #pragma unroll
    for (int m=0;m<2;m++) {
      int rbase = wm*32 + m*16 + kg*4;
      #pragma unroll
      for (int j=0;j<4;j++) {
        size_t off = (size_t)(rbase+j)*(SS*TT) + t;
        ob[off] = acc[m][n][j] + bv + bf2f(xb[off]);
      }
    }
  }
}

extern "C" void kernel_launch(void* const* d_in, const int* in_sizes, int n_in,
                              void* d_out, int out_size, void* d_ws, size_t ws_size,
                              hipStream_t stream) {
  (void)in_sizes; (void)n_in; (void)out_size; (void)ws_size;
  const float* x     = (const float*)d_in[0];
  const float* gamma = (const float*)d_in[1];
  const float* beta  = (const float*)d_in[2];
  const float* keys1 = (const float*)d_in[3];
  const float* Wp1   = (const float*)d_in[4];
  const float* bp1   = (const float*)d_in[5];
  const float* keys2 = (const float*)d_in[6];
  const float* Wp2   = (const float*)d_in[7];
  const float* bp2   = (const float*)d_in[8];
  float* out = (float*)d_out;
  char* ws = (char*)d_ws;

  // ws layout (bytes):
  float* sumt        = (float*)(ws + 0);              // 512 B
  float* sumsq       = (float*)(ws + 512);            // 512 B
  float* csum_part   = (float*)(ws + 1024);           // 1 MB (128 x 2048, transposed)
  float* ssq_part    = (float*)(ws + 1049600);        // 1 MB
  float* p2part      = (float*)(ws + 2098176);        // 4 MB (512 x 8 x 256)
  float* b1          = (float*)(ws + 6292480);        // 512 KB
  float* b2          = (float*)(ws + 6816768);        // 256 KB
  unsigned short* w1bf = (unsigned short*)(ws + 7078912);   // 33.5 MB
  unsigned short* w2bf = (unsigned short*)(ws + 40633344);  // 33.5 MB
  unsigned short* xbf  = (unsigned short*)(ws + 74187776);  // 67 MB
  unsigned short* zbf  = (unsigned short*)(ws + 141296640); // 134 MB -> end ~275 MB

  float* w1out = out + 33554432;
  float* w2out = out + 50331648;

  k1_stats  <<<BS*4, 256,  0, stream>>>(x, csum_part, ssq_part, xbf);
  k1b_reduce<<<TT,   256,  0, stream>>>(csum_part, ssq_part, sumt, sumsq);
  k2_route1 <<<BS*4, 256,  0, stream>>>(sumt, sumsq, csum_part, gamma, beta, keys1, Wp1, bp1,
                                        w1out, w1bf, b1);
  k3_gemm1  <<<BS*4, 512,  0, stream>>>(xbf, w1bf, b1, zbf, p2part);
  k4_route2 <<<BS*4, 256,  0, stream>>>(p2part, keys2, Wp2, bp2, w2out, w2bf, b2);
  k5_gemm2  <<<BS*4, 1024, 0, stream>>>(zbf, w2bf, b2, xbf, out);
}